// Round 1
// baseline (293.567 us; speedup 1.0000x reference)
//
#include <hip/hip_runtime.h>

#define NB 8
#define SS 2048
#define DD 128

static constexpr float SCALE = 0.08838834764831845f; // 1/sqrt(128)

// ---------------------------------------------------------------------------
// K1: W = SCALE * Q K^T (raw scores), 64x64 tile per block, D split in halves.
// LDS: QsT[64][68], KsT[64][68] transposed (k-major), padded stride 68 floats
// (272 B = 17*16 B: 16B-aligned rows, stride ≡ 4 mod 32 banks).
// grid (SS/64, SS/64, NB), block 256, dyn LDS 2*64*68*4 = 34816 B -> 4 blk/CU
// ---------------------------------------------------------------------------
__global__ __launch_bounds__(256, 4)
void qk_kernel(const float* __restrict__ Q, const float* __restrict__ K,
               float* __restrict__ W) {
  extern __shared__ float lds[];
  float* QsT = lds;             // [64 dd][68]
  float* KsT = lds + 64 * 68;   // [64 dd][68]
  const int b = blockIdx.z;
  const int qbase = blockIdx.y * 64;
  const int kbase = blockIdx.x * 64;
  const int tid = threadIdx.x;
  const float* Qb = Q + ((size_t)b * SS + qbase) * DD;
  const float* Kb = K + ((size_t)b * SS + kbase) * DD;
  const int ty = tid >> 4, tx = tid & 15;

  float acc[4][4] = {};

  for (int h = 0; h < 2; ++h) {
    // stage 64 rows x 64 dims, transposed into LDS
    for (int idx = tid; idx < 1024; idx += 256) {
      const int r4 = idx >> 6;       // 0..15 (row group of 4)
      const int dd = idx & 63;       // 0..63
      const int d = h * 64 + dd;
      float4 qv, kv;
      qv.x = Qb[(r4 * 4 + 0) * DD + d];
      qv.y = Qb[(r4 * 4 + 1) * DD + d];
      qv.z = Qb[(r4 * 4 + 2) * DD + d];
      qv.w = Qb[(r4 * 4 + 3) * DD + d];
      kv.x = Kb[(r4 * 4 + 0) * DD + d];
      kv.y = Kb[(r4 * 4 + 1) * DD + d];
      kv.z = Kb[(r4 * 4 + 2) * DD + d];
      kv.w = Kb[(r4 * 4 + 3) * DD + d];
      *reinterpret_cast<float4*>(&QsT[dd * 68 + r4 * 4]) = qv;
      *reinterpret_cast<float4*>(&KsT[dd * 68 + r4 * 4]) = kv;
    }
    __syncthreads();
    #pragma unroll 8
    for (int kk = 0; kk < 64; ++kk) {
      float4 a  = *reinterpret_cast<const float4*>(&QsT[kk * 68 + ty * 4]);
      float4 bb = *reinterpret_cast<const float4*>(&KsT[kk * 68 + tx * 4]);
      acc[0][0] += a.x * bb.x; acc[0][1] += a.x * bb.y;
      acc[0][2] += a.x * bb.z; acc[0][3] += a.x * bb.w;
      acc[1][0] += a.y * bb.x; acc[1][1] += a.y * bb.y;
      acc[1][2] += a.y * bb.z; acc[1][3] += a.y * bb.w;
      acc[2][0] += a.z * bb.x; acc[2][1] += a.z * bb.y;
      acc[2][2] += a.z * bb.z; acc[2][3] += a.z * bb.w;
      acc[3][0] += a.w * bb.x; acc[3][1] += a.w * bb.y;
      acc[3][2] += a.w * bb.z; acc[3][3] += a.w * bb.w;
    }
    __syncthreads();
  }

  float* Wb = W + (size_t)b * SS * SS;
  #pragma unroll
  for (int i = 0; i < 4; ++i) {
    float4 v = make_float4(acc[i][0] * SCALE, acc[i][1] * SCALE,
                           acc[i][2] * SCALE, acc[i][3] * SCALE);
    *reinterpret_cast<float4*>(
        &Wb[(size_t)(qbase + ty * 4 + i) * SS + kbase + tx * 4]) = v;
  }
}

// ---------------------------------------------------------------------------
// K1b: per-row max and 1/sum(exp(s-max)) -> stats[row] = {m, inv}
// grid (NB*SS), block 256 (one row per block, 8 elems/thread via float4)
// ---------------------------------------------------------------------------
__global__ __launch_bounds__(256)
void rowstat_kernel(const float* __restrict__ W, float2* __restrict__ stats) {
  const size_t row = blockIdx.x;
  const float* wr = W + row * SS;
  const int tid = threadIdx.x;
  float4 v0 = *reinterpret_cast<const float4*>(&wr[tid * 4]);
  float4 v1 = *reinterpret_cast<const float4*>(&wr[1024 + tid * 4]);
  float m = fmaxf(fmaxf(fmaxf(v0.x, v0.y), fmaxf(v0.z, v0.w)),
                  fmaxf(fmaxf(v1.x, v1.y), fmaxf(v1.z, v1.w)));
  #pragma unroll
  for (int o = 32; o > 0; o >>= 1) m = fmaxf(m, __shfl_xor(m, o));
  __shared__ float redm[4], reds[4];
  const int wid = tid >> 6;
  if ((tid & 63) == 0) redm[wid] = m;
  __syncthreads();
  m = fmaxf(fmaxf(redm[0], redm[1]), fmaxf(redm[2], redm[3]));
  float s = __expf(v0.x - m) + __expf(v0.y - m) + __expf(v0.z - m) +
            __expf(v0.w - m) + __expf(v1.x - m) + __expf(v1.y - m) +
            __expf(v1.z - m) + __expf(v1.w - m);
  #pragma unroll
  for (int o = 32; o > 0; o >>= 1) s += __shfl_xor(s, o);
  if ((tid & 63) == 0) reds[wid] = s;
  __syncthreads();
  if (tid == 0) {
    float tot = reds[0] + reds[1] + reds[2] + reds[3];
    stats[row] = make_float2(m, 1.0f / tot);
  }
}

// ---------------------------------------------------------------------------
// K2: normalize weights in place (p = exp(s-m)*inv) and Out = P V.
// Block: 32 q-rows x 128 d, loop k in tiles of 64.
// LDS: PsT[64 k][68] + Vs[64 k][132]  = 51200 B -> 3 blk/CU
// grid (SS/32, NB), block 256 (ty=tid>>5 rows, tx=tid&31 cols)
// ---------------------------------------------------------------------------
__global__ __launch_bounds__(256, 3)
void pv_kernel(float* __restrict__ W, const float* __restrict__ V,
               const float2* __restrict__ stats, float* __restrict__ Out) {
  extern __shared__ float lds[];
  float* PsT = lds;             // [64][68]
  float* Vs = lds + 64 * 68;    // [64][132]
  __shared__ float sm[32], si[32];
  const int b = blockIdx.y;
  const int qbase = blockIdx.x * 32;
  const int tid = threadIdx.x;
  float* Wb = W + ((size_t)b * SS + qbase) * SS;
  const float* Vb = V + (size_t)b * SS * DD;

  if (tid < 32) {
    float2 st = stats[(size_t)b * SS + qbase + tid];
    sm[tid] = st.x;
    si[tid] = st.y;
  }
  __syncthreads();

  const int ty = tid >> 5, tx = tid & 31;  // ty 0..7 (rows), tx 0..31 (cols)
  float acc[4][4] = {};

  for (int kt = 0; kt < 32; ++kt) {
    const int k0 = kt * 64;
    // stage P tile (32 rows x 64 k): normalize, write back, store transposed
    #pragma unroll
    for (int it = 0; it < 2; ++it) {
      const int idx = tid + it * 256;  // 0..511
      const int row = idx >> 4;        // 0..31
      const int c4 = idx & 15;         // 0..15
      float* wp = &Wb[(size_t)row * SS + k0 + c4 * 4];
      float4 v = *reinterpret_cast<const float4*>(wp);
      const float mrow = sm[row], irow = si[row];
      float4 p;
      p.x = __expf(v.x - mrow) * irow;
      p.y = __expf(v.y - mrow) * irow;
      p.z = __expf(v.z - mrow) * irow;
      p.w = __expf(v.w - mrow) * irow;
      *reinterpret_cast<float4*>(wp) = p;
      PsT[(c4 * 4 + 0) * 68 + row] = p.x;
      PsT[(c4 * 4 + 1) * 68 + row] = p.y;
      PsT[(c4 * 4 + 2) * 68 + row] = p.z;
      PsT[(c4 * 4 + 3) * 68 + row] = p.w;
    }
    // stage V tile (64 k x 128 d), row-major
    #pragma unroll
    for (int it = 0; it < 8; ++it) {
      const int idx = tid + it * 256;  // 0..2047
      const int k = idx >> 5;          // 0..63
      const int c4 = idx & 31;         // 0..31
      float4 v = *reinterpret_cast<const float4*>(
          &Vb[(size_t)(k0 + k) * DD + c4 * 4]);
      *reinterpret_cast<float4*>(&Vs[k * 132 + c4 * 4]) = v;
    }
    __syncthreads();
    #pragma unroll 8
    for (int k = 0; k < 64; ++k) {
      float4 a = *reinterpret_cast<const float4*>(&PsT[k * 68 + ty * 4]);
      float4 v = *reinterpret_cast<const float4*>(&Vs[k * 132 + tx * 4]);
      acc[0][0] += a.x * v.x; acc[0][1] += a.x * v.y;
      acc[0][2] += a.x * v.z; acc[0][3] += a.x * v.w;
      acc[1][0] += a.y * v.x; acc[1][1] += a.y * v.y;
      acc[1][2] += a.y * v.z; acc[1][3] += a.y * v.w;
      acc[2][0] += a.z * v.x; acc[2][1] += a.z * v.y;
      acc[2][2] += a.z * v.z; acc[2][3] += a.z * v.w;
      acc[3][0] += a.w * v.x; acc[3][1] += a.w * v.y;
      acc[3][2] += a.w * v.z; acc[3][3] += a.w * v.w;
    }
    __syncthreads();
  }

  float* ob = Out + ((size_t)b * SS + qbase) * DD;
  #pragma unroll
  for (int i = 0; i < 4; ++i) {
    float4 v = make_float4(acc[i][0], acc[i][1], acc[i][2], acc[i][3]);
    *reinterpret_cast<float4*>(&ob[(size_t)(ty * 4 + i) * DD + tx * 4]) = v;
  }
}

// ---------------------------------------------------------------------------
extern "C" void kernel_launch(void* const* d_in, const int* in_sizes, int n_in,
                              void* d_out, int out_size, void* d_ws,
                              size_t ws_size, hipStream_t stream) {
  const float* Q = (const float*)d_in[0];
  const float* K = (const float*)d_in[1];
  const float* V = (const float*)d_in[2];
  float* out = (float*)d_out;
  float* W = out + (size_t)NB * SS * DD;  // weights region of d_out
  float2* stats = (float2*)d_ws;          // 16384 * 8 B = 128 KB

  qk_kernel<<<dim3(SS / 64, SS / 64, NB), 256, 2 * 64 * 68 * 4, stream>>>(Q, K, W);
  rowstat_kernel<<<dim3(NB * SS), 256, 0, stream>>>(W, stats);
  pv_kernel<<<dim3(SS / 32, NB), 256, (64 * 68 + 64 * 132) * 4, stream>>>(
      W, V, stats, out);
}

// Round 2
// 179.296 us; speedup vs baseline: 1.6373x; 1.6373x over previous
//
#include <hip/hip_runtime.h>
#include <hip/hip_bf16.h>

#define NB 8
#define SS 2048
#define DD 128
#define NQK (NB * SS * DD)  // 2,097,152 elements per tensor

typedef __attribute__((ext_vector_type(8))) short bf16x8;
typedef __attribute__((ext_vector_type(16))) float f32x16;

static constexpr float SCALE = 0.08838834764831845f;  // 1/sqrt(128)

#define MFMA32(a, b, c) __builtin_amdgcn_mfma_f32_32x32x16_bf16(a, b, c, 0, 0, 0)

__device__ __forceinline__ unsigned short f2bf(float x) {
  __hip_bfloat16 h = __float2bfloat16(x);  // RNE
  unsigned short r;
  __builtin_memcpy(&r, &h, 2);
  return r;
}
__device__ __forceinline__ float bf2f(unsigned int u) {
  u = (u & 0xffffu) << 16;
  float f;
  __builtin_memcpy(&f, &u, 4);
  return f;
}

// ---------------------------------------------------------------------------
// K0a: fp32 -> (hi, lo) bf16 planes. 8 elems/thread, grid 1024 x 256.
// ---------------------------------------------------------------------------
__global__ __launch_bounds__(256) void convert_qk(const float* __restrict__ src,
                                                  unsigned short* __restrict__ hi,
                                                  unsigned short* __restrict__ lo) {
  const int i = blockIdx.x * 256 + threadIdx.x;  // 0..262143
  const float4* s4 = (const float4*)src;
  const float4 a = s4[2 * i], b = s4[2 * i + 1];
  const float v[8] = {a.x, a.y, a.z, a.w, b.x, b.y, b.z, b.w};
  bf16x8 H, L;
#pragma unroll
  for (int j = 0; j < 8; ++j) {
    const unsigned short h = f2bf(v[j]);
    H[j] = (short)h;
    L[j] = (short)f2bf(v[j] - bf2f(h));
  }
  ((bf16x8*)hi)[i] = H;
  ((bf16x8*)lo)[i] = L;
}

// ---------------------------------------------------------------------------
// K0b: V fp32 [b][k][d] -> Vt bf16 [b][d][k]  (single plane, RNE)
// grid (32 k-tiles of 64, 8 batches), block 256
// ---------------------------------------------------------------------------
__global__ __launch_bounds__(256) void transpose_v(const float* __restrict__ V,
                                                   unsigned short* __restrict__ Vt) {
  __shared__ __align__(16) unsigned short T[128][72];  // [d][k-tile 64], pad 72
  const int b = blockIdx.y, kb = blockIdx.x * 64;
  const int tid = threadIdx.x;
  {  // phase 1: load + convert + transpose-scatter into LDS
    const int k = tid >> 2, dseg = (tid & 3) * 32;
    const float4* src = (const float4*)(V + ((size_t)b * SS + kb + k) * DD + dseg);
#pragma unroll
    for (int q = 0; q < 8; ++q) {
      const float4 f = src[q];
      T[dseg + q * 4 + 0][k] = f2bf(f.x);
      T[dseg + q * 4 + 1][k] = f2bf(f.y);
      T[dseg + q * 4 + 2][k] = f2bf(f.z);
      T[dseg + q * 4 + 3][k] = f2bf(f.w);
    }
  }
  __syncthreads();
  {  // phase 2: coalesced row writes
    const int d = tid >> 1, kh = (tid & 1) * 32;
    unsigned short* dst = Vt + ((size_t)b * DD + d) * SS + kb + kh;
#pragma unroll
    for (int s = 0; s < 4; ++s)
      *(bf16x8*)(dst + s * 8) = *(const bf16x8*)&T[d][kh + s * 8];
  }
}

// ---------------------------------------------------------------------------
// K1: per-row (max, sumexp) partials via swapped MFMA S^T = K*Q^T.
// grid (16 q-blocks of 128, 8 key-splits of 256, 8 batches), block 256 (4 waves x 32q)
// ---------------------------------------------------------------------------
__global__ __launch_bounds__(256, 4)
void stats_kernel(const unsigned short* __restrict__ Qhi, const unsigned short* __restrict__ Qlo,
                  const unsigned short* __restrict__ Khi, const unsigned short* __restrict__ Klo,
                  float2* __restrict__ partials) {
  __shared__ __align__(16) unsigned short KsH[32][136];
  __shared__ __align__(16) unsigned short KsL[32][136];
  const int b = blockIdx.z, qb = blockIdx.x, ks = blockIdx.y;
  const int tid = threadIdx.x;
  const int lane = tid & 63, wv = tid >> 6;
  const int q0 = qb * 128 + wv * 32;
  const int lq = lane & 31, h2 = lane >> 5;
  const size_t Bo = (size_t)b * SS * DD;
  const f32x16 ZERO16 = {0, 0, 0, 0, 0, 0, 0, 0, 0, 0, 0, 0, 0, 0, 0, 0};

  // Q B-fragments (hi+lo) resident in registers: Q[q0+lq][ds*16 + h2*8 + j]
  const unsigned short* qph = Qhi + Bo + (size_t)(q0 + lq) * DD + h2 * 8;
  const unsigned short* qpl = Qlo + Bo + (size_t)(q0 + lq) * DD + h2 * 8;
  bf16x8 qh[8], ql[8];
#pragma unroll
  for (int ds = 0; ds < 8; ++ds) {
    qh[ds] = *(const bf16x8*)(qph + ds * 16);
    ql[ds] = *(const bf16x8*)(qpl + ds * 16);
  }

  const int srow = tid >> 3, sc0 = (tid & 7) * 8;
  float m = -1e30f, ssum = 0.f;

  for (int w = 0; w < 8; ++w) {
    const int kb = ks * 256 + w * 32;
#pragma unroll
    for (int it = 0; it < 2; ++it) {  // stage K tile 32k x 128d, both planes
      const int d0 = sc0 + it * 64;
      const size_t go = Bo + (size_t)(kb + srow) * DD + d0;
      *(bf16x8*)&KsH[srow][d0] = *(const bf16x8*)(Khi + go);
      *(bf16x8*)&KsL[srow][d0] = *(const bf16x8*)(Klo + go);
    }
    __syncthreads();
    f32x16 acc = ZERO16;
#pragma unroll
    for (int ds = 0; ds < 8; ++ds) {
      const bf16x8 ah = *(const bf16x8*)&KsH[lq][ds * 16 + h2 * 8];
      const bf16x8 al = *(const bf16x8*)&KsL[lq][ds * 16 + h2 * 8];
      acc = MFMA32(ah, qh[ds], acc);
      acc = MFMA32(ah, ql[ds], acc);
      acc = MFMA32(al, qh[ds], acc);
    }
    __syncthreads();
    // online softmax update over this lane's 16 scores (column q = lq)
    float tm = acc[0];
#pragma unroll
    for (int r = 1; r < 16; ++r) tm = fmaxf(tm, acc[r]);
    const float nm = fmaxf(m, tm * SCALE);
    float add = 0.f;
#pragma unroll
    for (int r = 0; r < 16; ++r) add += __expf(acc[r] * SCALE - nm);
    ssum = ssum * __expf(m - nm) + add;
    m = nm;
  }
  // combine the two half-wave partials (lanes l <-> l+32 share q)
  const float mo = __shfl_xor(m, 32);
  const float so = __shfl_xor(ssum, 32);
  const float nm = fmaxf(m, mo);
  ssum = ssum * __expf(m - nm) + so * __expf(mo - nm);
  if (h2 == 0)
    partials[((size_t)b * SS + q0 + lq) * 8 + ks] = make_float2(nm, ssum);
}

// ---------------------------------------------------------------------------
// K1b: combine 8 key-split partials -> stats[row] = {m, 1/sum}
// ---------------------------------------------------------------------------
__global__ __launch_bounds__(256) void reduce_stats(const float2* __restrict__ partials,
                                                    float2* __restrict__ stats) {
  const int r = blockIdx.x * 256 + threadIdx.x;  // 16384 rows
  float2 p[8];
  float m = -1e30f;
#pragma unroll
  for (int j = 0; j < 8; ++j) {
    p[j] = partials[(size_t)r * 8 + j];
    m = fmaxf(m, p[j].x);
  }
  float s = 0.f;
#pragma unroll
  for (int j = 0; j < 8; ++j) s += p[j].y * __expf(p[j].x - m);
  stats[r] = make_float2(m, 1.0f / s);
}

// ---------------------------------------------------------------------------
// K2: recompute S^T, normalize, write W (coalesced), and PV via MFMA.
// grid (16 q-blocks of 128, 8 key-splits of 256, 8 batches), block 256.
// Out accumulated with fp32 atomicAdd (memset to 0 first).
// ---------------------------------------------------------------------------
__global__ __launch_bounds__(256, 3)
void fused_kernel(const unsigned short* __restrict__ Qhi, const unsigned short* __restrict__ Qlo,
                  const unsigned short* __restrict__ Khi, const unsigned short* __restrict__ Klo,
                  const unsigned short* __restrict__ Vt, const float2* __restrict__ stats,
                  float* __restrict__ W, float* __restrict__ Out) {
  __shared__ __align__(16) unsigned short KsH[32][136];
  __shared__ __align__(16) unsigned short KsL[32][136];
  __shared__ __align__(16) unsigned short VTs[128][40];  // [d][k 32 + pad]
  __shared__ __align__(16) unsigned int Pb[4][32][20];   // per wave: [q 32][k-pairs 16 + pad]

  const int b = blockIdx.z, qb = blockIdx.x, ks = blockIdx.y;
  const int tid = threadIdx.x;
  const int lane = tid & 63, wv = tid >> 6;
  const int q0 = qb * 128 + wv * 32;
  const int lq = lane & 31, h2 = lane >> 5;
  const size_t Bo = (size_t)b * SS * DD;
  const f32x16 ZERO16 = {0, 0, 0, 0, 0, 0, 0, 0, 0, 0, 0, 0, 0, 0, 0, 0};

  const float2 st = stats[(size_t)b * SS + q0 + lq];
  const float mrow = st.x, inv = st.y;

  const unsigned short* qph = Qhi + Bo + (size_t)(q0 + lq) * DD + h2 * 8;
  const unsigned short* qpl = Qlo + Bo + (size_t)(q0 + lq) * DD + h2 * 8;
  bf16x8 qh[8];
#pragma unroll
  for (int ds = 0; ds < 8; ++ds) qh[ds] = *(const bf16x8*)(qph + ds * 16);

  f32x16 accO[4];
#pragma unroll
  for (int dt = 0; dt < 4; ++dt) accO[dt] = ZERO16;

  const int srow = tid >> 3, sc0 = (tid & 7) * 8;
  const int vd = tid >> 1, vh = (tid & 1) * 16;

  for (int w = 0; w < 8; ++w) {
    const int kb = ks * 256 + w * 32;
#pragma unroll
    for (int it = 0; it < 2; ++it) {  // stage K tile
      const int d0 = sc0 + it * 64;
      const size_t go = Bo + (size_t)(kb + srow) * DD + d0;
      *(bf16x8*)&KsH[srow][d0] = *(const bf16x8*)(Khi + go);
      *(bf16x8*)&KsL[srow][d0] = *(const bf16x8*)(Klo + go);
    }
    {  // stage V^T tile (row-copy from pre-transposed plane)
      const unsigned short* g = Vt + ((size_t)b * DD + vd) * SS + kb + vh;
      *(bf16x8*)&VTs[vd][vh] = *(const bf16x8*)g;
      *(bf16x8*)&VTs[vd][vh + 8] = *(const bf16x8*)(g + 8);
    }
    __syncthreads();
    // ---- QK^T (S^T tile, 3-term split-bf16); Q-lo streamed (L2-hot) ----
    f32x16 acc = ZERO16;
    bf16x8 qlc = *(const bf16x8*)(qpl);
#pragma unroll
    for (int ds = 0; ds < 8; ++ds) {
      bf16x8 qln;
      if (ds < 7) qln = *(const bf16x8*)(qpl + (ds + 1) * 16);
      const bf16x8 ah = *(const bf16x8*)&KsH[lq][ds * 16 + h2 * 8];
      const bf16x8 al = *(const bf16x8*)&KsL[lq][ds * 16 + h2 * 8];
      acc = MFMA32(ah, qh[ds], acc);
      acc = MFMA32(ah, qlc, acc);
      acc = MFMA32(al, qh[ds], acc);
      qlc = qln;
    }
    // ---- softmax-normalize; pack bf16 pairs into bounce buffer ----
    // D layout (verified): col(q)=lane&31, row(key)=(r&3)+8*(r>>2)+4*h2
#pragma unroll
    for (int g = 0; g < 4; ++g) {
      const float p0 = __expf(acc[4 * g + 0] * SCALE - mrow) * inv;
      const float p1 = __expf(acc[4 * g + 1] * SCALE - mrow) * inv;
      const float p2 = __expf(acc[4 * g + 2] * SCALE - mrow) * inv;
      const float p3 = __expf(acc[4 * g + 3] * SCALE - mrow) * inv;
      uint2 u;
      u.x = (unsigned)f2bf(p0) | ((unsigned)f2bf(p1) << 16);
      u.y = (unsigned)f2bf(p2) | ((unsigned)f2bf(p3) << 16);
      *(uint2*)&Pb[wv][lq][4 * g + 2 * h2] = u;
    }
    asm volatile("s_waitcnt lgkmcnt(0)" ::: "memory");
    // ---- coalesced W write (rows q0+row, cols kb + seg*16 .. +15) ----
    {
      const int row = lane >> 1, seg = lane & 1;
      const uint4 r0 = *(const uint4*)&Pb[wv][row][seg * 8];
      const uint4 r1 = *(const uint4*)&Pb[wv][row][seg * 8 + 4];
      float* wp = W + ((size_t)b * SS + q0 + row) * SS + kb + seg * 16;
      float4 o;
      o.x = bf2f(r0.x); o.y = bf2f(r0.x >> 16); o.z = bf2f(r0.y); o.w = bf2f(r0.y >> 16);
      *(float4*)(wp + 0) = o;
      o.x = bf2f(r0.z); o.y = bf2f(r0.z >> 16); o.z = bf2f(r0.w); o.w = bf2f(r0.w >> 16);
      *(float4*)(wp + 4) = o;
      o.x = bf2f(r1.x); o.y = bf2f(r1.x >> 16); o.z = bf2f(r1.y); o.w = bf2f(r1.y >> 16);
      *(float4*)(wp + 8) = o;
      o.x = bf2f(r1.z); o.y = bf2f(r1.z >> 16); o.z = bf2f(r1.w); o.w = bf2f(r1.w >> 16);
      *(float4*)(wp + 12) = o;
    }
    // ---- PV: accO[dt] += P(16k) * V^T ----
#pragma unroll
    for (int kk = 0; kk < 2; ++kk) {
      const bf16x8 pa = *(const bf16x8*)&Pb[wv][lq][kk * 8 + 4 * h2];
#pragma unroll
      for (int dt = 0; dt < 4; ++dt) {
        const bf16x8 vb = *(const bf16x8*)&VTs[dt * 32 + lq][kk * 16 + 8 * h2];
        accO[dt] = MFMA32(pa, vb, accO[dt]);
      }
    }
    __syncthreads();
  }
  // ---- accumulate partial PV into Out (8 key-splits per location) ----
#pragma unroll
  for (int dt = 0; dt < 4; ++dt) {
#pragma unroll
    for (int g = 0; g < 4; ++g) {
#pragma unroll
      for (int j = 0; j < 4; ++j) {
        const int qq = q0 + j + 8 * g + 4 * h2;
        atomicAdd(&Out[((size_t)b * SS + qq) * DD + dt * 32 + lq], accO[dt][4 * g + j]);
      }
    }
  }
}

// ---------------------------------------------------------------------------
extern "C" void kernel_launch(void* const* d_in, const int* in_sizes, int n_in,
                              void* d_out, int out_size, void* d_ws, size_t ws_size,
                              hipStream_t stream) {
  const float* Q = (const float*)d_in[0];
  const float* K = (const float*)d_in[1];
  const float* V = (const float*)d_in[2];
  float* out = (float*)d_out;
  float* W = out + (size_t)NQK;  // attn_weights region of d_out

  char* ws = (char*)d_ws;  // ~21.2 MB used
  unsigned short* Qhi = (unsigned short*)(ws);
  unsigned short* Qlo = (unsigned short*)(ws + ((size_t)4 << 20));
  unsigned short* Khi = (unsigned short*)(ws + ((size_t)8 << 20));
  unsigned short* Klo = (unsigned short*)(ws + ((size_t)12 << 20));
  unsigned short* Vt  = (unsigned short*)(ws + ((size_t)16 << 20));
  float2* partials = (float2*)(ws + ((size_t)20 << 20));
  float2* stats = (float2*)(ws + ((size_t)21 << 20));

  hipMemsetAsync(out, 0, (size_t)NQK * sizeof(float), stream);
  convert_qk<<<1024, 256, 0, stream>>>(Q, Qhi, Qlo);
  convert_qk<<<1024, 256, 0, stream>>>(K, Khi, Klo);
  transpose_v<<<dim3(32, 8), 256, 0, stream>>>(V, Vt);
  stats_kernel<<<dim3(16, 8, 8), 256, 0, stream>>>(Qhi, Qlo, Khi, Klo, partials);
  reduce_stats<<<64, 256, 0, stream>>>(partials, stats);
  fused_kernel<<<dim3(16, 8, 8), 256, 0, stream>>>(Qhi, Qlo, Khi, Klo, Vt, stats, W, out);
}

// Round 3
// 131.620 us; speedup vs baseline: 2.2304x; 1.3622x over previous
//
#include <hip/hip_runtime.h>
#include <hip/hip_bf16.h>

#define NB 8
#define SS 2048
#define DD 128

typedef __attribute__((ext_vector_type(8))) short bf16x8;
typedef __attribute__((ext_vector_type(16))) float f32x16;

static constexpr float SCALE = 0.08838834764831845f;  // 1/sqrt(128)

#define MFMA32(a, b, c) __builtin_amdgcn_mfma_f32_32x32x16_bf16(a, b, c, 0, 0, 0)

__device__ __forceinline__ unsigned short f2bf(float x) {
  __hip_bfloat16 h = __float2bfloat16(x);  // RNE
  unsigned short r;
  __builtin_memcpy(&r, &h, 2);
  return r;
}

// ---------------------------------------------------------------------------
// K0a: Q,K fp32 -> bf16 (single hi plane). grid (1024, 2), 8 elems/thread.
// ---------------------------------------------------------------------------
__global__ __launch_bounds__(256) void conv_qk(const float* __restrict__ Q,
                                               const float* __restrict__ K,
                                               unsigned short* __restrict__ Qh,
                                               unsigned short* __restrict__ Kh) {
  const float* s = blockIdx.y ? K : Q;
  unsigned short* d = blockIdx.y ? Kh : Qh;
  const int i = blockIdx.x * 256 + threadIdx.x;  // 0..262143
  const float4 a = ((const float4*)s)[2 * i];
  const float4 b = ((const float4*)s)[2 * i + 1];
  bf16x8 H;
  H[0] = (short)f2bf(a.x); H[1] = (short)f2bf(a.y);
  H[2] = (short)f2bf(a.z); H[3] = (short)f2bf(a.w);
  H[4] = (short)f2bf(b.x); H[5] = (short)f2bf(b.y);
  H[6] = (short)f2bf(b.z); H[7] = (short)f2bf(b.w);
  ((bf16x8*)d)[i] = H;
}

// ---------------------------------------------------------------------------
// K0b: V fp32 [b][k][d] -> Vt bf16 [b][d][k]. grid (32, 8), block 256.
// ---------------------------------------------------------------------------
__global__ __launch_bounds__(256) void transpose_v(const float* __restrict__ V,
                                                   unsigned short* __restrict__ Vt) {
  __shared__ __align__(16) unsigned short T[128][72];
  const int b = blockIdx.y, kb = blockIdx.x * 64;
  const int tid = threadIdx.x;
  {
    const int k = tid >> 2, dseg = (tid & 3) * 32;
    const float4* src = (const float4*)(V + ((size_t)b * SS + kb + k) * DD + dseg);
#pragma unroll
    for (int q = 0; q < 8; ++q) {
      const float4 f = src[q];
      T[dseg + q * 4 + 0][k] = f2bf(f.x);
      T[dseg + q * 4 + 1][k] = f2bf(f.y);
      T[dseg + q * 4 + 2][k] = f2bf(f.z);
      T[dseg + q * 4 + 3][k] = f2bf(f.w);
    }
  }
  __syncthreads();
  {
    const int d = tid >> 1, kh = (tid & 1) * 32;
    unsigned short* dst = Vt + ((size_t)b * DD + d) * SS + kb + kh;
#pragma unroll
    for (int s = 0; s < 4; ++s)
      *(bf16x8*)(dst + s * 8) = *(const bf16x8*)&T[d][kh + s * 8];
  }
}

// ---------------------------------------------------------------------------
// K1: per-row (max, sumexp) partials. LDS-free, barrier-free.
// grid (16 qb, 8 ks, 8 b), block 256 = 4 waves (each its own 32 q rows).
// ---------------------------------------------------------------------------
__global__ __launch_bounds__(256)
void stats_kernel(const unsigned short* __restrict__ Qh,
                  const unsigned short* __restrict__ Kh,
                  float2* __restrict__ partials) {
  const int b = blockIdx.z, qb = blockIdx.x, ks = blockIdx.y;
  const int tid = threadIdx.x;
  const int lane = tid & 63, wv = tid >> 6;
  const int q0 = qb * 128 + wv * 32;
  const int lq = lane & 31, h2 = lane >> 5;
  const size_t Bo = (size_t)b * SS * DD;
  const f32x16 ZERO16 = {0, 0, 0, 0, 0, 0, 0, 0, 0, 0, 0, 0, 0, 0, 0, 0};

  const unsigned short* qp = Qh + Bo + (size_t)(q0 + lq) * DD + h2 * 8;
  bf16x8 qh[8];
#pragma unroll
  for (int ds = 0; ds < 8; ++ds) qh[ds] = *(const bf16x8*)(qp + ds * 16);

  float m = -1e30f, ssum = 0.f;
  for (int w = 0; w < 8; ++w) {
    const int kb = ks * 256 + w * 32;
    const unsigned short* kp = Kh + Bo + (size_t)(kb + lq) * DD + h2 * 8;
    f32x16 acc = ZERO16;
#pragma unroll
    for (int ds = 0; ds < 8; ++ds) {
      const bf16x8 ah = *(const bf16x8*)(kp + ds * 16);
      acc = MFMA32(ah, qh[ds], acc);
    }
    float tm = acc[0];
#pragma unroll
    for (int r = 1; r < 16; ++r) tm = fmaxf(tm, acc[r]);
    const float nm = fmaxf(m, tm * SCALE);
    float add = 0.f;
#pragma unroll
    for (int r = 0; r < 16; ++r) add += __expf(acc[r] * SCALE - nm);
    ssum = ssum * __expf(m - nm) + add;
    m = nm;
  }
  const float mo = __shfl_xor(m, 32);
  const float so = __shfl_xor(ssum, 32);
  const float nm = fmaxf(m, mo);
  ssum = ssum * __expf(m - nm) + so * __expf(mo - nm);
  if (h2 == 0)
    partials[((size_t)b * SS + q0 + lq) * 8 + ks] = make_float2(nm, ssum);
}

// ---------------------------------------------------------------------------
// K1b: combine 8 key-split partials -> stats[row] = {m, 1/sum}
// ---------------------------------------------------------------------------
__global__ __launch_bounds__(256) void reduce_stats(const float2* __restrict__ partials,
                                                    float2* __restrict__ stats) {
  const int r = blockIdx.x * 256 + threadIdx.x;  // 16384 rows
  float2 p[8];
  float m = -1e30f;
#pragma unroll
  for (int j = 0; j < 8; ++j) {
    p[j] = partials[(size_t)r * 8 + j];
    m = fmaxf(m, p[j].x);
  }
  float s = 0.f;
#pragma unroll
  for (int j = 0; j < 8; ++j) s += p[j].y * __expf(p[j].x - m);
  stats[r] = make_float2(m, 1.0f / s);
}

// ---------------------------------------------------------------------------
// K2: fused normalize + W write + PV. Barrier-free main loop.
// grid (64 qb, 8 b), block 256 = 4 waves = 4-way k-split (512 keys each).
// All K/V reads straight from global (L2-resident). W stores fp32 direct
// from accumulator. O reduced 4-way in LDS at the end.
// ---------------------------------------------------------------------------
__global__ __launch_bounds__(256, 2)
void fused_kernel(const unsigned short* __restrict__ Qh,
                  const unsigned short* __restrict__ Kh,
                  const unsigned short* __restrict__ Vt,
                  const float2* __restrict__ stats,
                  float* __restrict__ W, float* __restrict__ Out) {
  __shared__ __align__(16) unsigned int Pb[4][32][20];  // per-wave P bounce
  __shared__ __align__(16) float R[32][132];            // O reduction

  const int b = blockIdx.y, qb = blockIdx.x;
  const int q0 = qb * 32;
  const int tid = threadIdx.x;
  const int lane = tid & 63, wv = tid >> 6;
  const int lq = lane & 31, h2 = lane >> 5;
  const size_t Bo = (size_t)b * SS * DD;
  const f32x16 ZERO16 = {0, 0, 0, 0, 0, 0, 0, 0, 0, 0, 0, 0, 0, 0, 0, 0};

  const float2 st = stats[(size_t)b * SS + q0 + lq];
  const float mrow = st.x, inv = st.y;

  const unsigned short* qp = Qh + Bo + (size_t)(q0 + lq) * DD + h2 * 8;
  bf16x8 qh[8];
#pragma unroll
  for (int ds = 0; ds < 8; ++ds) qh[ds] = *(const bf16x8*)(qp + ds * 16);

  f32x16 accO[4];
#pragma unroll
  for (int dt = 0; dt < 4; ++dt) accO[dt] = ZERO16;

  float* const wrow = W + ((size_t)b * SS + q0 + lq) * SS;

  for (int kt = 0; kt < 16; ++kt) {
    const int kb = wv * 512 + kt * 32;
    // ---- S^T = K * Q^T over this wave's 32-key slice ----
    const unsigned short* kp = Kh + Bo + (size_t)(kb + lq) * DD + h2 * 8;
    f32x16 acc = ZERO16;
#pragma unroll
    for (int ds = 0; ds < 8; ++ds) {
      const bf16x8 ah = *(const bf16x8*)(kp + ds * 16);
      acc = MFMA32(ah, qh[ds], acc);
    }
    // ---- normalize, direct fp32 W store, pack bf16 for PV ----
    // D layout: col(q)=lq, key row = (r&3) + 8*(r>>2) + 4*h2
#pragma unroll
    for (int g = 0; g < 4; ++g) {
      const float p0 = __expf(acc[4 * g + 0] * SCALE - mrow) * inv;
      const float p1 = __expf(acc[4 * g + 1] * SCALE - mrow) * inv;
      const float p2 = __expf(acc[4 * g + 2] * SCALE - mrow) * inv;
      const float p3 = __expf(acc[4 * g + 3] * SCALE - mrow) * inv;
      *(float4*)(wrow + kb + 8 * g + 4 * h2) = make_float4(p0, p1, p2, p3);
      uint2 u;
      u.x = (unsigned)f2bf(p0) | ((unsigned)f2bf(p1) << 16);
      u.y = (unsigned)f2bf(p2) | ((unsigned)f2bf(p3) << 16);
      *(uint2*)&Pb[wv][lq][4 * g + 2 * h2] = u;
    }
    // ---- PV: accO[dt] += P(32k slice) * V^T ----
#pragma unroll
    for (int kk = 0; kk < 2; ++kk) {
      const bf16x8 pa = *(const bf16x8*)&Pb[wv][lq][kk * 8 + 4 * h2];
#pragma unroll
      for (int dt = 0; dt < 4; ++dt) {
        const bf16x8 vb = *(const bf16x8*)(
            Vt + ((size_t)b * DD + dt * 32 + lq) * SS + kb + kk * 16 + 8 * h2);
        accO[dt] = MFMA32(pa, vb, accO[dt]);
      }
    }
  }

  // ---- 4-way O reduction in LDS (only barriers in the kernel) ----
  __syncthreads();
#pragma unroll
  for (int ph = 0; ph < 4; ++ph) {
    if (wv == ph) {
#pragma unroll
      for (int dt = 0; dt < 4; ++dt) {
#pragma unroll
        for (int r = 0; r < 16; ++r) {
          const int q = (r & 3) + 8 * (r >> 2) + 4 * h2;
          const int d = dt * 32 + lq;
          if (ph == 0) R[q][d] = accO[dt][r];
          else         R[q][d] += accO[dt][r];
        }
      }
    }
    __syncthreads();
  }
  {
    const int row = tid >> 3, c0 = (tid & 7) * 16;
    float* ob = Out + ((size_t)b * SS + q0 + row) * DD + c0;
#pragma unroll
    for (int j = 0; j < 4; ++j)
      *(float4*)(ob + 4 * j) = *(const float4*)&R[row][c0 + 4 * j];
  }
}

// ---------------------------------------------------------------------------
extern "C" void kernel_launch(void* const* d_in, const int* in_sizes, int n_in,
                              void* d_out, int out_size, void* d_ws, size_t ws_size,
                              hipStream_t stream) {
  const float* Q = (const float*)d_in[0];
  const float* K = (const float*)d_in[1];
  const float* V = (const float*)d_in[2];
  float* out = (float*)d_out;
  float* W = out + (size_t)NB * SS * DD;  // attn_weights region of d_out

  char* ws = (char*)d_ws;  // ~13.2 MB used
  unsigned short* Qh = (unsigned short*)(ws);
  unsigned short* Kh = (unsigned short*)(ws + ((size_t)4 << 20));
  unsigned short* Vt = (unsigned short*)(ws + ((size_t)8 << 20));
  float2* partials = (float2*)(ws + ((size_t)12 << 20));
  float2* stats = (float2*)(ws + ((size_t)13 << 20));

  conv_qk<<<dim3(1024, 2), 256, 0, stream>>>(Q, K, Qh, Kh);
  transpose_v<<<dim3(32, 8), 256, 0, stream>>>(V, Vt);
  stats_kernel<<<dim3(16, 8, 8), 256, 0, stream>>>(Qh, Kh, partials);
  reduce_stats<<<64, 256, 0, stream>>>(partials, stats);
  fused_kernel<<<dim3(64, 8), 256, 0, stream>>>(Qh, Kh, Vt, stats, W, out);
}

// Round 4
// 86.097 us; speedup vs baseline: 3.4097x; 1.5287x over previous
//
#include <hip/hip_runtime.h>
#include <hip/hip_bf16.h>

#define NB 8
#define SS 2048
#define DD 128

typedef __attribute__((ext_vector_type(8))) short bf16x8;
typedef __attribute__((ext_vector_type(16))) float f32x16;

static constexpr float SCALE = 0.08838834764831845f;  // 1/sqrt(128)
static constexpr float C1 = 0.08838834764831845f * 1.4426950408889634f;  // SCALE*log2(e)

#define MFMA32(a, b, c) __builtin_amdgcn_mfma_f32_32x32x16_bf16(a, b, c, 0, 0, 0)

#if __has_builtin(__builtin_amdgcn_exp2f)
#define EXP2 __builtin_amdgcn_exp2f
#else
#define EXP2 exp2f
#endif

__device__ __forceinline__ unsigned short f2bf(float x) {
  __hip_bfloat16 h = __float2bfloat16(x);  // RNE
  unsigned short r;
  __builtin_memcpy(&r, &h, 2);
  return r;
}

// ---------------------------------------------------------------------------
// prep: fp32 -> bf16 fragment-tiled layouts.
//   role 0/1 (Q/K): T[b][tile32][16 ck][32 lq][8]  elem = X[b][t*32+lq][ck*8+j]
//   role 2   (V):   T[b][tile32][4 c][128 d][8]    elem = V[b][t*32+c*8+j][d]
// grid (64 tiles, 8 b, 3 roles), block 256.
// ---------------------------------------------------------------------------
__global__ __launch_bounds__(256)
void prep_kernel(const float* __restrict__ Q, const float* __restrict__ K,
                 const float* __restrict__ V, unsigned short* __restrict__ Qt,
                 unsigned short* __restrict__ Kt, unsigned short* __restrict__ Vt) {
  __shared__ __align__(16) float Tf[32][132];
  const int ti = blockIdx.x, b = blockIdx.y, role = blockIdx.z;
  const int tid = threadIdx.x;
  const float* src = role == 0 ? Q : (role == 1 ? K : V);
  {  // coalesced 32x128 fp32 tile load
    const int row = tid >> 3, seg = (tid & 7) * 16;
    const float4* sp = (const float4*)(src + ((size_t)b * SS + ti * 32 + row) * DD + seg);
#pragma unroll
    for (int j = 0; j < 4; ++j) *(float4*)&Tf[row][seg + 4 * j] = sp[j];
  }
  __syncthreads();
  if (role < 2) {
    unsigned short* dst = (role == 0 ? Qt : Kt) + ((size_t)b * 64 + ti) * 4096;
#pragma unroll
    for (int e = 0; e < 2; ++e) {
      const int c = 2 * tid + e, lq = c & 31, ck = c >> 5;
      const float4 a = *(const float4*)&Tf[lq][ck * 8];
      const float4 d = *(const float4*)&Tf[lq][ck * 8 + 4];
      bf16x8 o;
      o[0] = (short)f2bf(a.x); o[1] = (short)f2bf(a.y);
      o[2] = (short)f2bf(a.z); o[3] = (short)f2bf(a.w);
      o[4] = (short)f2bf(d.x); o[5] = (short)f2bf(d.y);
      o[6] = (short)f2bf(d.z); o[7] = (short)f2bf(d.w);
      *(bf16x8*)(dst + c * 8) = o;
    }
  } else {
    unsigned short* dst = Vt + ((size_t)b * 64 + ti) * 4096;
#pragma unroll
    for (int e = 0; e < 2; ++e) {
      const int chunk = 2 * tid + e, cc = chunk >> 7, d = chunk & 127;
      bf16x8 o;
#pragma unroll
      for (int j = 0; j < 8; ++j) o[j] = (short)f2bf(Tf[cc * 8 + j][d]);
      *(bf16x8*)(dst + chunk * 8) = o;
    }
  }
}

// ---------------------------------------------------------------------------
// stats: per-row (max2, sum2) partials in exp2 domain, swapped MFMA S^T=K*Q^T.
// grid (16 qb of 128 rows, 16 ks of 128 keys, 8 b), block 256 = 4 waves.
// ---------------------------------------------------------------------------
__global__ __launch_bounds__(256, 4)
void stats_kernel(const unsigned short* __restrict__ Qt,
                  const unsigned short* __restrict__ Kt,
                  float2* __restrict__ partials) {
  const int b = blockIdx.z, qb = blockIdx.x, ks = blockIdx.y;
  const int tid = threadIdx.x;
  const int lane = tid & 63, wv = tid >> 6;
  const int lq = lane & 31, h2 = lane >> 5;
  const int q0t = qb * 4 + wv;  // 32-row q-tile index
  const f32x16 ZERO16 = {0, 0, 0, 0, 0, 0, 0, 0, 0, 0, 0, 0, 0, 0, 0, 0};

  const unsigned short* qbase = Qt + ((size_t)b * 64 + q0t) * 4096;
  bf16x8 qh[8];
#pragma unroll
  for (int ds = 0; ds < 8; ++ds)
    qh[ds] = *(const bf16x8*)(qbase + ((ds * 2 + h2) * 32 + lq) * 8);

  float m2 = -1e30f, s2 = 0.f;
#pragma unroll
  for (int kt = 0; kt < 4; ++kt) {
    const int kti = ks * 4 + kt;
    const unsigned short* kbase = Kt + ((size_t)b * 64 + kti) * 4096;
    f32x16 acc = ZERO16;
#pragma unroll
    for (int ds = 0; ds < 8; ++ds) {
      const bf16x8 ah = *(const bf16x8*)(kbase + ((ds * 2 + h2) * 32 + lq) * 8);
      acc = MFMA32(ah, qh[ds], acc);
    }
    float tm = acc[0];
#pragma unroll
    for (int r = 1; r < 16; ++r) tm = fmaxf(tm, acc[r]);
    const float nm2 = fmaxf(m2, tm * C1);
    float add = 0.f;
#pragma unroll
    for (int r = 0; r < 16; ++r) add += EXP2(fmaf(acc[r], C1, -nm2));
    s2 = s2 * EXP2(m2 - nm2) + add;
    m2 = nm2;
  }
  const float mo = __shfl_xor(m2, 32);
  const float so = __shfl_xor(s2, 32);
  const float nm = fmaxf(m2, mo);
  s2 = s2 * EXP2(m2 - nm) + so * EXP2(mo - nm);
  if (h2 == 0)
    partials[((size_t)b * SS + q0t * 32 + lq) * 16 + ks] = make_float2(nm, s2);
}

// ---------------------------------------------------------------------------
// fused: combine partials -> lb; recompute S^T; W = exp2(fma(s,C1,lb));
// PV via MFMA from fragment-tiled Vt. Barrier-free main loop.
// grid (64 qb of 32 rows, 8 b), block 256 = 4 waves = 4-way k-split.
// ---------------------------------------------------------------------------
__global__ __launch_bounds__(256, 2)
void fused_kernel(const unsigned short* __restrict__ Qt,
                  const unsigned short* __restrict__ Kt,
                  const unsigned short* __restrict__ Vt,
                  const float2* __restrict__ partials,
                  float* __restrict__ W, float* __restrict__ Out) {
  __shared__ __align__(16) unsigned int Pb[4][32][20];
  __shared__ __align__(16) float R[32][132];
  __shared__ float lbs[32];

  const int b = blockIdx.y, qb = blockIdx.x;
  const int q0 = qb * 32;
  const int tid = threadIdx.x;
  const int lane = tid & 63, wv = tid >> 6;
  const int lq = lane & 31, h2 = lane >> 5;
  const f32x16 ZERO16 = {0, 0, 0, 0, 0, 0, 0, 0, 0, 0, 0, 0, 0, 0, 0, 0};

  // ---- prologue: combine 16 key-split partials -> lb per row ----
  if (tid < 32) {
    const float2* pp = partials + ((size_t)b * SS + q0 + tid) * 16;
    float2 p[16];
    float m = -1e30f;
#pragma unroll
    for (int j = 0; j < 16; ++j) {
      p[j] = pp[j];
      m = fmaxf(m, p[j].x);
    }
    float s = 0.f;
#pragma unroll
    for (int j = 0; j < 16; ++j) s += p[j].y * EXP2(p[j].x - m);
    lbs[tid] = -(m + __log2f(s));
  }
  {
    float* Rf = &R[0][0];
    for (int idx = tid; idx < 32 * 132; idx += 256) Rf[idx] = 0.f;
  }
  __syncthreads();

  const unsigned short* qbase = Qt + ((size_t)b * 64 + (q0 >> 5)) * 4096;
  bf16x8 qh[8];
#pragma unroll
  for (int ds = 0; ds < 8; ++ds)
    qh[ds] = *(const bf16x8*)(qbase + ((ds * 2 + h2) * 32 + lq) * 8);
  const float lb = lbs[lq];

  f32x16 accO[4];
#pragma unroll
  for (int dt = 0; dt < 4; ++dt) accO[dt] = ZERO16;

  float* const wrow = W + ((size_t)b * SS + q0 + lq) * SS;

  for (int kt = 0; kt < 16; ++kt) {
    const int kti = wv * 16 + kt;  // this wave's 32-key tile
    const int kb = kti * 32;
    const unsigned short* kbase = Kt + ((size_t)b * 64 + kti) * 4096;
    // ---- QK^T: S^T tile via swapped MFMA ----
    bf16x8 ah[8];
#pragma unroll
    for (int ds = 0; ds < 8; ++ds)
      ah[ds] = *(const bf16x8*)(kbase + ((ds * 2 + h2) * 32 + lq) * 8);
    f32x16 acc = ZERO16;
#pragma unroll
    for (int ds = 0; ds < 8; ++ds) acc = MFMA32(ah[ds], qh[ds], acc);
    // ---- softmax: p = exp2(s*C1 + lb); W store; pack bf16 pairs ----
    // D layout: col(q)=lq, key row = (r&3) + 8*(r>>2) + 4*h2
#pragma unroll
    for (int g = 0; g < 4; ++g) {
      const float p0 = EXP2(fmaf(acc[4 * g + 0], C1, lb));
      const float p1 = EXP2(fmaf(acc[4 * g + 1], C1, lb));
      const float p2 = EXP2(fmaf(acc[4 * g + 2], C1, lb));
      const float p3 = EXP2(fmaf(acc[4 * g + 3], C1, lb));
      *(float4*)(wrow + kb + 8 * g + 4 * h2) = make_float4(p0, p1, p2, p3);
      uint2 u;
      u.x = (unsigned)f2bf(p0) | ((unsigned)f2bf(p1) << 16);
      u.y = (unsigned)f2bf(p2) | ((unsigned)f2bf(p3) << 16);
      *(uint2*)&Pb[wv][lq][4 * g + 2 * h2] = u;
    }
    asm volatile("s_waitcnt lgkmcnt(0)" ::: "memory");
    // ---- PV from fragment-tiled Vt (coalesced dwordx4 loads) ----
    const unsigned short* vtile = Vt + ((size_t)b * 64 + kti) * 4096;
#pragma unroll
    for (int kk = 0; kk < 2; ++kk) {
      const bf16x8 pa = *(const bf16x8*)&Pb[wv][lq][kk * 8 + 4 * h2];
#pragma unroll
      for (int dt = 0; dt < 4; ++dt) {
        const bf16x8 vb = *(const bf16x8*)(
            vtile + ((kk * 2 + h2) * 128 + dt * 32 + lq) * 8);
        accO[dt] = MFMA32(pa, vb, accO[dt]);
      }
    }
  }

  // ---- 4-way O reduction in LDS ----
  __syncthreads();
#pragma unroll
  for (int ph = 0; ph < 4; ++ph) {
    if (wv == ph) {
#pragma unroll
      for (int dt = 0; dt < 4; ++dt) {
#pragma unroll
        for (int r = 0; r < 16; ++r) {
          const int q = (r & 3) + 8 * (r >> 2) + 4 * h2;
          const int d = dt * 32 + lq;
          R[q][d] += accO[dt][r];
        }
      }
    }
    __syncthreads();
  }
  {
    const int row = tid >> 3, c0 = (tid & 7) * 16;
    float* ob = Out + ((size_t)b * SS + q0 + row) * DD + c0;
#pragma unroll
    for (int j = 0; j < 4; ++j)
      *(float4*)(ob + 4 * j) = *(const float4*)&R[row][c0 + 4 * j];
  }
}

// ---------------------------------------------------------------------------
extern "C" void kernel_launch(void* const* d_in, const int* in_sizes, int n_in,
                              void* d_out, int out_size, void* d_ws, size_t ws_size,
                              hipStream_t stream) {
  const float* Q = (const float*)d_in[0];
  const float* K = (const float*)d_in[1];
  const float* V = (const float*)d_in[2];
  float* out = (float*)d_out;
  float* W = out + (size_t)NB * SS * DD;  // attn_weights region of d_out

  char* ws = (char*)d_ws;  // 14 MB used
  unsigned short* Qt = (unsigned short*)(ws);
  unsigned short* Kt = (unsigned short*)(ws + ((size_t)4 << 20));
  unsigned short* Vt = (unsigned short*)(ws + ((size_t)8 << 20));
  float2* partials = (float2*)(ws + ((size_t)12 << 20));

  prep_kernel<<<dim3(64, 8, 3), 256, 0, stream>>>(Q, K, V, Qt, Kt, Vt);
  stats_kernel<<<dim3(16, 16, 8), 256, 0, stream>>>(Qt, Kt, partials);
  fused_kernel<<<dim3(64, 8), 256, 0, stream>>>(Qt, Kt, Vt, partials, W, out);
}

// Round 5
// 80.381 us; speedup vs baseline: 3.6522x; 1.0711x over previous
//
#include <hip/hip_runtime.h>
#include <hip/hip_bf16.h>

#define NB 8
#define SS 2048
#define DD 128
#define NQK (NB * SS * DD)

typedef __attribute__((ext_vector_type(8))) short bf16x8;
typedef __attribute__((ext_vector_type(16))) float f32x16;
typedef __attribute__((ext_vector_type(4))) unsigned int uint4v;
typedef __attribute__((ext_vector_type(2))) unsigned int uint2v;

static constexpr float C1 = 0.08838834764831845f * 1.4426950408889634f;  // SCALE*log2(e)

#define MFMA32(a, b, c) __builtin_amdgcn_mfma_f32_32x32x16_bf16(a, b, c, 0, 0, 0)
#define PSWAP(a, b) __builtin_amdgcn_permlane32_swap(a, b, false, false)

#if __has_builtin(__builtin_amdgcn_exp2f)
#define EXP2 __builtin_amdgcn_exp2f
#else
#define EXP2 exp2f
#endif

__device__ __forceinline__ unsigned short f2bf(float x) {
  __hip_bfloat16 h = __float2bfloat16(x);  // RNE
  unsigned short r;
  __builtin_memcpy(&r, &h, 2);
  return r;
}

// ---------------------------------------------------------------------------
// prep: fp32 -> bf16 fragment-tiled layouts.
//   role 0/1 (Q/K): T[b][tile32][16 ck][32 lq][8]  elem = X[b][t*32+lq][ck*8+j]
//   role 2   (V):   T[b][tile32][4 c][128 d][8]    elem = V[b][t*32+c*8+j][d]
// grid (64 tiles, 8 b, 3 roles), block 256.
// ---------------------------------------------------------------------------
__global__ __launch_bounds__(256)
void prep_kernel(const float* __restrict__ Q, const float* __restrict__ K,
                 const float* __restrict__ V, unsigned short* __restrict__ Qt,
                 unsigned short* __restrict__ Kt, unsigned short* __restrict__ Vt) {
  __shared__ __align__(16) float Tf[32][132];
  const int ti = blockIdx.x, b = blockIdx.y, role = blockIdx.z;
  const int tid = threadIdx.x;
  const float* src = role == 0 ? Q : (role == 1 ? K : V);
  {
    const int row = tid >> 3, seg = (tid & 7) * 16;
    const float4* sp = (const float4*)(src + ((size_t)b * SS + ti * 32 + row) * DD + seg);
#pragma unroll
    for (int j = 0; j < 4; ++j) *(float4*)&Tf[row][seg + 4 * j] = sp[j];
  }
  __syncthreads();
  if (role < 2) {
    unsigned short* dst = (role == 0 ? Qt : Kt) + ((size_t)b * 64 + ti) * 4096;
#pragma unroll
    for (int e = 0; e < 2; ++e) {
      const int c = 2 * tid + e, lq = c & 31, ck = c >> 5;
      const float4 a = *(const float4*)&Tf[lq][ck * 8];
      const float4 d = *(const float4*)&Tf[lq][ck * 8 + 4];
      bf16x8 o;
      o[0] = (short)f2bf(a.x); o[1] = (short)f2bf(a.y);
      o[2] = (short)f2bf(a.z); o[3] = (short)f2bf(a.w);
      o[4] = (short)f2bf(d.x); o[5] = (short)f2bf(d.y);
      o[6] = (short)f2bf(d.z); o[7] = (short)f2bf(d.w);
      *(bf16x8*)(dst + c * 8) = o;
    }
  } else {
    unsigned short* dst = Vt + ((size_t)b * 64 + ti) * 4096;
#pragma unroll
    for (int e = 0; e < 2; ++e) {
      const int chunk = 2 * tid + e, cc = chunk >> 7, d = chunk & 127;
      bf16x8 o;
#pragma unroll
      for (int j = 0; j < 8; ++j) o[j] = (short)f2bf(Tf[cc * 8 + j][d]);
      *(bf16x8*)(dst + chunk * 8) = o;
    }
  }
}

// ---------------------------------------------------------------------------
// stats: per-row (max2, sum2) partials in exp2 domain, swapped MFMA S^T=K*Q^T.
// 2-tile ILP: two independent MFMA accumulator chains keep the matrix pipe fed.
// grid (16 qb of 128 rows, 16 ks of 128 keys, 8 b), block 256 = 4 waves.
// ---------------------------------------------------------------------------
__global__ __launch_bounds__(256, 2)
void stats_kernel(const unsigned short* __restrict__ Qt,
                  const unsigned short* __restrict__ Kt,
                  float2* __restrict__ partials) {
  const int b = blockIdx.z, qb = blockIdx.x, ks = blockIdx.y;
  const int tid = threadIdx.x;
  const int lane = tid & 63, wv = tid >> 6;
  const int lq = lane & 31, h2 = lane >> 5;
  const int q0t = qb * 4 + wv;
  const f32x16 ZERO16 = {0, 0, 0, 0, 0, 0, 0, 0, 0, 0, 0, 0, 0, 0, 0, 0};

  const unsigned short* qbase = Qt + ((size_t)b * 64 + q0t) * 4096;
  bf16x8 qh[8];
#pragma unroll
  for (int ds = 0; ds < 8; ++ds)
    qh[ds] = *(const bf16x8*)(qbase + ((ds * 2 + h2) * 32 + lq) * 8);

  float m2 = -1e30f, s2 = 0.f;
#pragma unroll
  for (int kp = 0; kp < 2; ++kp) {
    const unsigned short* kb0 = Kt + ((size_t)b * 64 + ks * 4 + 2 * kp) * 4096;
    const unsigned short* kb1 = kb0 + 4096;
    bf16x8 a0[8], a1[8];
#pragma unroll
    for (int ds = 0; ds < 8; ++ds) {
      a0[ds] = *(const bf16x8*)(kb0 + ((ds * 2 + h2) * 32 + lq) * 8);
      a1[ds] = *(const bf16x8*)(kb1 + ((ds * 2 + h2) * 32 + lq) * 8);
    }
    f32x16 acc0 = ZERO16, acc1 = ZERO16;
#pragma unroll
    for (int ds = 0; ds < 8; ++ds) {
      acc0 = MFMA32(a0[ds], qh[ds], acc0);
      acc1 = MFMA32(a1[ds], qh[ds], acc1);
    }
    float tm0 = acc0[0], tm1 = acc1[0];
#pragma unroll
    for (int r = 1; r < 16; ++r) {
      tm0 = fmaxf(tm0, acc0[r]);
      tm1 = fmaxf(tm1, acc1[r]);
    }
    const float nm2 = fmaxf(m2, fmaxf(tm0, tm1) * C1);
    float add = 0.f;
#pragma unroll
    for (int r = 0; r < 16; ++r)
      add += EXP2(fmaf(acc0[r], C1, -nm2)) + EXP2(fmaf(acc1[r], C1, -nm2));
    s2 = s2 * EXP2(m2 - nm2) + add;
    m2 = nm2;
  }
  const float mo = __shfl_xor(m2, 32);
  const float so = __shfl_xor(s2, 32);
  const float nm = fmaxf(m2, mo);
  s2 = s2 * EXP2(m2 - nm) + so * EXP2(mo - nm);
  if (h2 == 0)
    partials[((size_t)b * SS + q0t * 32 + lq) * 16 + ks] = make_float2(nm, s2);
}

// ---------------------------------------------------------------------------
// fused: combine partials -> lb; recompute S^T (pipelined 1 tile ahead);
// W = exp2(fma(s,C1,lb)); P redistributed lane<->lane+32 via permlane32_swap
// (no LDS in main loop); PV via MFMA from fragment-tiled Vt.
// grid (64 qb of 32 rows, 8 b), block 256 = 4 waves = 4-way k-split.
// ---------------------------------------------------------------------------
__global__ __launch_bounds__(256, 2)
void fused_kernel(const unsigned short* __restrict__ Qt,
                  const unsigned short* __restrict__ Kt,
                  const unsigned short* __restrict__ Vt,
                  const float2* __restrict__ partials,
                  float* __restrict__ W, float* __restrict__ Out) {
  __shared__ __align__(16) float R[32][132];
  __shared__ float lbs[32];

  const int b = blockIdx.y, qb = blockIdx.x;
  const int q0 = qb * 32;
  const int tid = threadIdx.x;
  const int lane = tid & 63, wv = tid >> 6;
  const int lq = lane & 31, h2 = lane >> 5;
  const f32x16 ZERO16 = {0, 0, 0, 0, 0, 0, 0, 0, 0, 0, 0, 0, 0, 0, 0, 0};

  // ---- prologue: combine 16 key-split partials -> lb per row ----
  if (tid < 32) {
    const float2* pp = partials + ((size_t)b * SS + q0 + tid) * 16;
    float2 p[16];
    float m = -1e30f;
#pragma unroll
    for (int j = 0; j < 16; ++j) {
      p[j] = pp[j];
      m = fmaxf(m, p[j].x);
    }
    float s = 0.f;
#pragma unroll
    for (int j = 0; j < 16; ++j) s += p[j].y * EXP2(p[j].x - m);
    lbs[tid] = -(m + __log2f(s));
  }
  {
    float* Rf = &R[0][0];
    for (int idx = tid; idx < 32 * 132; idx += 256) Rf[idx] = 0.f;
  }
  __syncthreads();

  const unsigned short* qbase = Qt + ((size_t)b * 64 + (q0 >> 5)) * 4096;
  bf16x8 qh[8];
#pragma unroll
  for (int ds = 0; ds < 8; ++ds)
    qh[ds] = *(const bf16x8*)(qbase + ((ds * 2 + h2) * 32 + lq) * 8);
  const float lb = lbs[lq];

  f32x16 accO[4];
#pragma unroll
  for (int dt = 0; dt < 4; ++dt) accO[dt] = ZERO16;

  float* const wrow = W + ((size_t)b * SS + q0 + lq) * SS;
  const unsigned short* const ktw = Kt + ((size_t)b * 64 + wv * 16) * 4096;

  // pipeline prologue: QK for this wave's tile 0
  f32x16 acc = ZERO16;
  {
    bf16x8 ah[8];
#pragma unroll
    for (int ds = 0; ds < 8; ++ds)
      ah[ds] = *(const bf16x8*)(ktw + ((ds * 2 + h2) * 32 + lq) * 8);
#pragma unroll
    for (int ds = 0; ds < 8; ++ds) acc = MFMA32(ah[ds], qh[ds], acc);
  }

  for (int kt = 0; kt < 16; ++kt) {
    const int kti = wv * 16 + kt;
    // ---- prefetch next K tile fragments ----
    bf16x8 ahn[8];
    if (kt < 15) {
      const unsigned short* kn = ktw + (kt + 1) * 4096;
#pragma unroll
      for (int ds = 0; ds < 8; ++ds)
        ahn[ds] = *(const bf16x8*)(kn + ((ds * 2 + h2) * 32 + lq) * 8);
    }
    // ---- softmax on acc: p = exp2(s*C1 + lb); W store; pack bf16 pairs ----
    // D layout: col(q)=lq, key row = (r&3) + 8*(r>>2) + 4*h2
    unsigned int U[8];
    const int kb = kti * 32;
#pragma unroll
    for (int g = 0; g < 4; ++g) {
      const float p0 = EXP2(fmaf(acc[4 * g + 0], C1, lb));
      const float p1 = EXP2(fmaf(acc[4 * g + 1], C1, lb));
      const float p2 = EXP2(fmaf(acc[4 * g + 2], C1, lb));
      const float p3 = EXP2(fmaf(acc[4 * g + 3], C1, lb));
      *(float4*)(wrow + kb + 8 * g + 4 * h2) = make_float4(p0, p1, p2, p3);
      U[2 * g] = (unsigned)f2bf(p0) | ((unsigned)f2bf(p1) << 16);
      U[2 * g + 1] = (unsigned)f2bf(p2) | ((unsigned)f2bf(p3) << 16);
    }
    // ---- next tile's QK (independent chain: overlaps softmax + PV) ----
    f32x16 accn = ZERO16;
    if (kt < 15) {
#pragma unroll
      for (int ds = 0; ds < 8; ++ds) accn = MFMA32(ahn[ds], qh[ds], accn);
    }
    // ---- P redistribution via permlane32_swap (lane l <-> l+32) ----
    // pa(kk): lane needs keys kk*16 + h2*8 + 0..7
    const uint2v s02 = PSWAP(U[0], U[2]);
    const uint2v s13 = PSWAP(U[1], U[3]);
    const uint2v s46 = PSWAP(U[4], U[6]);
    const uint2v s57 = PSWAP(U[5], U[7]);
    uint4v w0, w1;
    w0.x = s02.x; w0.y = s13.x; w0.z = s02.y; w0.w = s13.y;
    w1.x = s46.x; w1.y = s57.x; w1.z = s46.y; w1.w = s57.y;
    const bf16x8 pa0 = __builtin_bit_cast(bf16x8, w0);
    const bf16x8 pa1 = __builtin_bit_cast(bf16x8, w1);
    // ---- PV from fragment-tiled Vt ----
    const unsigned short* vtile = Vt + ((size_t)b * 64 + kti) * 4096;
#pragma unroll
    for (int dt = 0; dt < 4; ++dt) {
      const bf16x8 vb0 = *(const bf16x8*)(vtile + ((h2)*128 + dt * 32 + lq) * 8);
      accO[dt] = MFMA32(pa0, vb0, accO[dt]);
    }
#pragma unroll
    for (int dt = 0; dt < 4; ++dt) {
      const bf16x8 vb1 = *(const bf16x8*)(vtile + ((2 + h2) * 128 + dt * 32 + lq) * 8);
      accO[dt] = MFMA32(pa1, vb1, accO[dt]);
    }
    acc = accn;
  }

  // ---- 4-way O reduction in LDS ----
  __syncthreads();
#pragma unroll
  for (int ph = 0; ph < 4; ++ph) {
    if (wv == ph) {
#pragma unroll
      for (int dt = 0; dt < 4; ++dt) {
#pragma unroll
        for (int r = 0; r < 16; ++r) {
          const int q = (r & 3) + 8 * (r >> 2) + 4 * h2;
          R[q][dt * 32 + lq] += accO[dt][r];
        }
      }
    }
    __syncthreads();
  }
  {
    const int row = tid >> 3, c0 = (tid & 7) * 16;
    float* ob = Out + ((size_t)b * SS + q0 + row) * DD + c0;
#pragma unroll
    for (int j = 0; j < 4; ++j)
      *(float4*)(ob + 4 * j) = *(const float4*)&R[row][c0 + 4 * j];
  }
}

// ---------------------------------------------------------------------------
extern "C" void kernel_launch(void* const* d_in, const int* in_sizes, int n_in,
                              void* d_out, int out_size, void* d_ws, size_t ws_size,
                              hipStream_t stream) {
  const float* Q = (const float*)d_in[0];
  const float* K = (const float*)d_in[1];
  const float* V = (const float*)d_in[2];
  float* out = (float*)d_out;
  float* W = out + (size_t)NQK;  // attn_weights region of d_out

  char* ws = (char*)d_ws;  // 14 MB used
  unsigned short* Qt = (unsigned short*)(ws);
  unsigned short* Kt = (unsigned short*)(ws + ((size_t)4 << 20));
  unsigned short* Vt = (unsigned short*)(ws + ((size_t)8 << 20));
  float2* partials = (float2*)(ws + ((size_t)12 << 20));

  prep_kernel<<<dim3(64, 8, 3), 256, 0, stream>>>(Q, K, V, Qt, Kt, Vt);
  stats_kernel<<<dim3(16, 16, 8), 256, 0, stream>>>(Qt, Kt, partials);
  fused_kernel<<<dim3(64, 8), 256, 0, stream>>>(Qt, Kt, Vt, partials, W, out);
}

// Round 7
// 72.818 us; speedup vs baseline: 4.0315x; 1.1039x over previous
//
#include <hip/hip_runtime.h>
#include <hip/hip_bf16.h>

#define NB 8
#define SS 2048
#define DD 128
#define NQK (NB * SS * DD)

typedef __attribute__((ext_vector_type(8))) short bf16x8;
typedef __attribute__((ext_vector_type(16))) float f32x16;
typedef __attribute__((ext_vector_type(4))) float f32x4;
typedef __attribute__((ext_vector_type(4))) unsigned int uint4v;
typedef __attribute__((ext_vector_type(2))) unsigned int uint2v;

static constexpr float C1 = 0.08838834764831845f * 1.4426950408889634f;  // SCALE*log2(e)

#define MFMA32(a, b, c) __builtin_amdgcn_mfma_f32_32x32x16_bf16(a, b, c, 0, 0, 0)
#define PSWAP(a, b) __builtin_amdgcn_permlane32_swap(a, b, false, false)

#if __has_builtin(__builtin_amdgcn_exp2f)
#define EXP2 __builtin_amdgcn_exp2f
#else
#define EXP2 exp2f
#endif

__device__ __forceinline__ unsigned short f2bf(float x) {
  __hip_bfloat16 h = __float2bfloat16(x);  // RNE
  unsigned short r;
  __builtin_memcpy(&r, &h, 2);
  return r;
}

__device__ __forceinline__ void nt_store4(const float* src, float* dst) {
  f32x4 v;
  __builtin_memcpy(&v, src, 16);
  __builtin_nontemporal_store(v, (f32x4*)dst);
}

// ---------------------------------------------------------------------------
// prep: fp32 -> bf16 fragment-tiled layouts.
//   role 0/1 (Q/K): T[b][tile32][16 ck][32 lq][8]  elem = X[b][t*32+lq][ck*8+j]
//   role 2   (V):   T[b][tile32][4 c][128 d][8]    elem = V[b][t*32+c*8+j][d]
// grid (64 tiles, 8 b, 3 roles), block 256.
// ---------------------------------------------------------------------------
__global__ __launch_bounds__(256)
void prep_kernel(const float* __restrict__ Q, const float* __restrict__ K,
                 const float* __restrict__ V, unsigned short* __restrict__ Qt,
                 unsigned short* __restrict__ Kt, unsigned short* __restrict__ Vt) {
  __shared__ __align__(16) float Tf[32][132];
  const int ti = blockIdx.x, b = blockIdx.y, role = blockIdx.z;
  const int tid = threadIdx.x;
  const float* src = role == 0 ? Q : (role == 1 ? K : V);
  {
    const int row = tid >> 3, seg = (tid & 7) * 16;
    const float4* sp = (const float4*)(src + ((size_t)b * SS + ti * 32 + row) * DD + seg);
#pragma unroll
    for (int j = 0; j < 4; ++j) *(float4*)&Tf[row][seg + 4 * j] = sp[j];
  }
  __syncthreads();
  if (role < 2) {
    unsigned short* dst = (role == 0 ? Qt : Kt) + ((size_t)b * 64 + ti) * 4096;
#pragma unroll
    for (int e = 0; e < 2; ++e) {
      const int c = 2 * tid + e, lq = c & 31, ck = c >> 5;
      const float4 a = *(const float4*)&Tf[lq][ck * 8];
      const float4 d = *(const float4*)&Tf[lq][ck * 8 + 4];
      bf16x8 o;
      o[0] = (short)f2bf(a.x); o[1] = (short)f2bf(a.y);
      o[2] = (short)f2bf(a.z); o[3] = (short)f2bf(a.w);
      o[4] = (short)f2bf(d.x); o[5] = (short)f2bf(d.y);
      o[6] = (short)f2bf(d.z); o[7] = (short)f2bf(d.w);
      *(bf16x8*)(dst + c * 8) = o;
    }
  } else {
    unsigned short* dst = Vt + ((size_t)b * 64 + ti) * 4096;
#pragma unroll
    for (int e = 0; e < 2; ++e) {
      const int chunk = 2 * tid + e, cc = chunk >> 7, d = chunk & 127;
      bf16x8 o;
#pragma unroll
      for (int j = 0; j < 8; ++j) o[j] = (short)f2bf(Tf[cc * 8 + j][d]);
      *(bf16x8*)(dst + chunk * 8) = o;
    }
  }
}

// ---------------------------------------------------------------------------
// stats: per-row (max2, sum2) partials in exp2 domain, swapped MFMA S^T=K*Q^T.
// grid (16 qb of 128 rows, 16 ks of 128 keys, 8 b), block 256 = 4 waves.
// ---------------------------------------------------------------------------
__global__ __launch_bounds__(256, 3)
void stats_kernel(const unsigned short* __restrict__ Qt,
                  const unsigned short* __restrict__ Kt,
                  float2* __restrict__ partials) {
  const int b = blockIdx.z, qb = blockIdx.x, ks = blockIdx.y;
  const int tid = threadIdx.x;
  const int lane = tid & 63, wv = tid >> 6;
  const int lq = lane & 31, h2 = lane >> 5;
  const int q0t = qb * 4 + wv;
  const f32x16 ZERO16 = {0, 0, 0, 0, 0, 0, 0, 0, 0, 0, 0, 0, 0, 0, 0, 0};

  const unsigned short* qbase = Qt + ((size_t)b * 64 + q0t) * 4096;
  bf16x8 qh[8];
#pragma unroll
  for (int ds = 0; ds < 8; ++ds)
    qh[ds] = *(const bf16x8*)(qbase + ((ds * 2 + h2) * 32 + lq) * 8);

  float m2 = -1e30f, s2 = 0.f;
#pragma unroll
  for (int kp = 0; kp < 2; ++kp) {
    const unsigned short* kb0 = Kt + ((size_t)b * 64 + ks * 4 + 2 * kp) * 4096;
    const unsigned short* kb1 = kb0 + 4096;
    bf16x8 a0[8], a1[8];
#pragma unroll
    for (int ds = 0; ds < 8; ++ds) {
      a0[ds] = *(const bf16x8*)(kb0 + ((ds * 2 + h2) * 32 + lq) * 8);
      a1[ds] = *(const bf16x8*)(kb1 + ((ds * 2 + h2) * 32 + lq) * 8);
    }
    f32x16 acc0 = ZERO16, acc1 = ZERO16;
#pragma unroll
    for (int ds = 0; ds < 8; ++ds) {
      acc0 = MFMA32(a0[ds], qh[ds], acc0);
      acc1 = MFMA32(a1[ds], qh[ds], acc1);
    }
    float tm0 = acc0[0], tm1 = acc1[0];
#pragma unroll
    for (int r = 1; r < 16; ++r) {
      tm0 = fmaxf(tm0, acc0[r]);
      tm1 = fmaxf(tm1, acc1[r]);
    }
    const float nm2 = fmaxf(m2, fmaxf(tm0, tm1) * C1);
    float add = 0.f;
#pragma unroll
    for (int r = 0; r < 16; ++r)
      add += EXP2(fmaf(acc0[r], C1, -nm2)) + EXP2(fmaf(acc1[r], C1, -nm2));
    s2 = s2 * EXP2(m2 - nm2) + add;
    m2 = nm2;
  }
  const float mo = __shfl_xor(m2, 32);
  const float so = __shfl_xor(s2, 32);
  const float nm = fmaxf(m2, mo);
  s2 = s2 * EXP2(m2 - nm) + so * EXP2(mo - nm);
  if (h2 == 0)
    partials[((size_t)b * SS + q0t * 32 + lq) * 16 + ks] = make_float2(nm, s2);
}

// ---------------------------------------------------------------------------
// fused: combine partials -> lb; recompute S^T (pipelined 1 tile ahead);
// W = exp2(fma(s,C1,lb)) stored nontemporal via per-wave LDS gather
// (8 rows x 128B full-line segments per store instr, vs 32x32B scatter);
// P redistributed lane<->lane+32 via permlane32_swap; PV from fragment-tiled
// Vt with V-frags prefetched one tile ahead.
// grid (64 qb of 32 rows, 8 b), block 256 = 4 waves = 4-way k-split.
// ---------------------------------------------------------------------------
__global__ __launch_bounds__(256, 2)
void fused_kernel(const unsigned short* __restrict__ Qt,
                  const unsigned short* __restrict__ Kt,
                  const unsigned short* __restrict__ Vt,
                  const float2* __restrict__ partials,
                  float* __restrict__ W, float* __restrict__ Out) {
  __shared__ __align__(16) float PW[4][32][40];  // per-wave P gather, rotated cols
  __shared__ __align__(16) float R[32][132];
  __shared__ float lbs[32];

  const int b = blockIdx.y, qb = blockIdx.x;
  const int q0 = qb * 32;
  const int tid = threadIdx.x;
  const int lane = tid & 63, wv = tid >> 6;
  const int lq = lane & 31, h2 = lane >> 5;
  const f32x16 ZERO16 = {0, 0, 0, 0, 0, 0, 0, 0, 0, 0, 0, 0, 0, 0, 0, 0};

  // ---- prologue: combine 16 key-split partials -> lb per row ----
  if (tid < 32) {
    const float2* pp = partials + ((size_t)b * SS + q0 + tid) * 16;
    float2 p[16];
    float m = -1e30f;
#pragma unroll
    for (int j = 0; j < 16; ++j) {
      p[j] = pp[j];
      m = fmaxf(m, p[j].x);
    }
    float s = 0.f;
#pragma unroll
    for (int j = 0; j < 16; ++j) s += p[j].y * EXP2(p[j].x - m);
    lbs[tid] = -(m + __log2f(s));
  }
  {
    float* Rf = &R[0][0];
    for (int idx = tid; idx < 32 * 132; idx += 256) Rf[idx] = 0.f;
  }
  __syncthreads();

  const unsigned short* qbase = Qt + ((size_t)b * 64 + (q0 >> 5)) * 4096;
  bf16x8 qh[8];
#pragma unroll
  for (int ds = 0; ds < 8; ++ds)
    qh[ds] = *(const bf16x8*)(qbase + ((ds * 2 + h2) * 32 + lq) * 8);
  const float lb = lbs[lq];

  // ---- W-store gather pointers (per-lane constants) ----
  // write: lane (lq,h2) puts its float4 g at PW[wv][lq][(8g+4h2+lq*4)&31]
  // read : lane (gq8,gks), instr i -> row=i*8+gq8, cols gks*4.. from rotated slot
  float* pwwr[4];
#pragma unroll
  for (int g = 0; g < 4; ++g)
    pwwr[g] = &PW[wv][lq][(8 * g + 4 * h2 + lq * 4) & 31];
  const int gq8 = lane >> 3, gks = lane & 7;
  const float* pwrd[4];
  float* wgb[4];
#pragma unroll
  for (int i = 0; i < 4; ++i) {
    const int row = i * 8 + gq8;
    pwrd[i] = &PW[wv][row][(gks * 4 + row * 4) & 31];
    wgb[i] = W + ((size_t)b * SS + q0 + row) * SS + gks * 4;
  }

  f32x16 accO[4];
#pragma unroll
  for (int dt = 0; dt < 4; ++dt) accO[dt] = ZERO16;

  const unsigned short* const ktw = Kt + ((size_t)b * 64 + wv * 16) * 4096;
  const unsigned short* const vtw = Vt + ((size_t)b * 64 + wv * 16) * 4096;

  // pipeline prologue: QK + V-frag loads for this wave's tile 0
  f32x16 acc = ZERO16;
  bf16x8 vb[8];
  {
    bf16x8 ah[8];
#pragma unroll
    for (int ds = 0; ds < 8; ++ds)
      ah[ds] = *(const bf16x8*)(ktw + ((ds * 2 + h2) * 32 + lq) * 8);
#pragma unroll
    for (int ds = 0; ds < 8; ++ds) acc = MFMA32(ah[ds], qh[ds], acc);
#pragma unroll
    for (int kk = 0; kk < 2; ++kk)
#pragma unroll
      for (int dt = 0; dt < 4; ++dt)
        vb[kk * 4 + dt] =
            *(const bf16x8*)(vtw + ((kk * 2 + h2) * 128 + dt * 32 + lq) * 8);
  }

  for (int kt = 0; kt < 16; ++kt) {
    const int kb = (wv * 16 + kt) * 32;
    // ---- prefetch next tile's K and V fragments ----
    bf16x8 ahn[8], vbn[8];
    if (kt < 15) {
      const unsigned short* kn = ktw + (kt + 1) * 4096;
      const unsigned short* vn = vtw + (kt + 1) * 4096;
#pragma unroll
      for (int ds = 0; ds < 8; ++ds)
        ahn[ds] = *(const bf16x8*)(kn + ((ds * 2 + h2) * 32 + lq) * 8);
#pragma unroll
      for (int kk = 0; kk < 2; ++kk)
#pragma unroll
        for (int dt = 0; dt < 4; ++dt)
          vbn[kk * 4 + dt] =
              *(const bf16x8*)(vn + ((kk * 2 + h2) * 128 + dt * 32 + lq) * 8);
    }
    // ---- softmax: p = exp2(s*C1 + lb); LDS gather write; bf16 pack ----
    // D layout: col(q)=lq, key row = (r&3) + 8*(r>>2) + 4*h2
    unsigned int U[8];
#pragma unroll
    for (int g = 0; g < 4; ++g) {
      const float p0 = EXP2(fmaf(acc[4 * g + 0], C1, lb));
      const float p1 = EXP2(fmaf(acc[4 * g + 1], C1, lb));
      const float p2 = EXP2(fmaf(acc[4 * g + 2], C1, lb));
      const float p3 = EXP2(fmaf(acc[4 * g + 3], C1, lb));
      *(float4*)pwwr[g] = make_float4(p0, p1, p2, p3);
      U[2 * g] = (unsigned)f2bf(p0) | ((unsigned)f2bf(p1) << 16);
      U[2 * g + 1] = (unsigned)f2bf(p2) | ((unsigned)f2bf(p3) << 16);
    }
    // ---- next tile's QK (independent; also hides the LDS write latency) ----
    f32x16 accn = ZERO16;
    if (kt < 15) {
#pragma unroll
      for (int ds = 0; ds < 8; ++ds) accn = MFMA32(ahn[ds], qh[ds], accn);
    }
    // ---- gathered nontemporal W stores (full-line segments) ----
#pragma unroll
    for (int i = 0; i < 4; ++i) nt_store4(pwrd[i], wgb[i] + kb);
    // ---- P redistribution via permlane32_swap (lane l <-> l+32) ----
    const uint2v s02 = PSWAP(U[0], U[2]);
    const uint2v s13 = PSWAP(U[1], U[3]);
    const uint2v s46 = PSWAP(U[4], U[6]);
    const uint2v s57 = PSWAP(U[5], U[7]);
    uint4v w0, w1;
    w0.x = s02.x; w0.y = s13.x; w0.z = s02.y; w0.w = s13.y;
    w1.x = s46.x; w1.y = s57.x; w1.z = s46.y; w1.w = s57.y;
    const bf16x8 pa0 = __builtin_bit_cast(bf16x8, w0);
    const bf16x8 pa1 = __builtin_bit_cast(bf16x8, w1);
    // ---- PV (V-frags prefetched last iter) ----
#pragma unroll
    for (int dt = 0; dt < 4; ++dt) accO[dt] = MFMA32(pa0, vb[dt], accO[dt]);
#pragma unroll
    for (int dt = 0; dt < 4; ++dt) accO[dt] = MFMA32(pa1, vb[4 + dt], accO[dt]);
    acc = accn;
#pragma unroll
    for (int j = 0; j < 8; ++j) vb[j] = vbn[j];
  }

  // ---- 4-way O reduction in LDS ----
  __syncthreads();
#pragma unroll
  for (int ph = 0; ph < 4; ++ph) {
    if (wv == ph) {
#pragma unroll
      for (int dt = 0; dt < 4; ++dt) {
#pragma unroll
        for (int r = 0; r < 16; ++r) {
          const int q = (r & 3) + 8 * (r >> 2) + 4 * h2;
          R[q][dt * 32 + lq] += accO[dt][r];
        }
      }
    }
    __syncthreads();
  }
  {
    const int row = tid >> 3, c0 = (tid & 7) * 16;
    float* ob = Out + ((size_t)b * SS + q0 + row) * DD + c0;
#pragma unroll
    for (int j = 0; j < 4; ++j) nt_store4(&R[row][c0 + 4 * j], ob + 4 * j);
  }
}

// ---------------------------------------------------------------------------
extern "C" void kernel_launch(void* const* d_in, const int* in_sizes, int n_in,
                              void* d_out, int out_size, void* d_ws, size_t ws_size,
                              hipStream_t stream) {
  const float* Q = (const float*)d_in[0];
  const float* K = (const float*)d_in[1];
  const float* V = (const float*)d_in[2];
  float* out = (float*)d_out;
  float* W = out + (size_t)NQK;  // attn_weights region of d_out

  char* ws = (char*)d_ws;  // 14 MB used
  unsigned short* Qt = (unsigned short*)(ws);
  unsigned short* Kt = (unsigned short*)(ws + ((size_t)4 << 20));
  unsigned short* Vt = (unsigned short*)(ws + ((size_t)8 << 20));
  float2* partials = (float2*)(ws + ((size_t)12 << 20));

  prep_kernel<<<dim3(64, 8, 3), 256, 0, stream>>>(Q, K, V, Qt, Kt, Vt);
  stats_kernel<<<dim3(16, 16, 8), 256, 0, stream>>>(Qt, Kt, partials);
  fused_kernel<<<dim3(64, 8), 256, 0, stream>>>(Qt, Kt, Vt, partials, W, out);
}

// Round 8
// 66.601 us; speedup vs baseline: 4.4079x; 1.0933x over previous
//
#include <hip/hip_runtime.h>
#include <hip/hip_bf16.h>

#define NB 8
#define SS 2048
#define DD 128
#define NQK (NB * SS * DD)

typedef __attribute__((ext_vector_type(8))) short bf16x8;
typedef __attribute__((ext_vector_type(16))) float f32x16;
typedef __attribute__((ext_vector_type(4))) float f32x4;
typedef __attribute__((ext_vector_type(4))) unsigned int uint4v;
typedef __attribute__((ext_vector_type(2))) unsigned int uint2v;

static constexpr float C1 = 0.08838834764831845f * 1.4426950408889634f;  // SCALE*log2(e)

#define MFMA32(a, b, c) __builtin_amdgcn_mfma_f32_32x32x16_bf16(a, b, c, 0, 0, 0)
#define PSWAP(a, b) __builtin_amdgcn_permlane32_swap(a, b, false, false)

#if __has_builtin(__builtin_amdgcn_exp2f)
#define EXP2 __builtin_amdgcn_exp2f
#else
#define EXP2 exp2f
#endif

__device__ __forceinline__ unsigned short f2bf(float x) {
  __hip_bfloat16 h = __float2bfloat16(x);  // RNE
  unsigned short r;
  __builtin_memcpy(&r, &h, 2);
  return r;
}

__device__ __forceinline__ void nt_store4(const float* src, float* dst) {
  f32x4 v;
  __builtin_memcpy(&v, src, 16);
  __builtin_nontemporal_store(v, (f32x4*)dst);
}

// ---------------------------------------------------------------------------
// prep: fp32 -> bf16 fragment-tiled layouts.
//   role 0/1 (Q/K): T[b][tile32][16 ck][32 lq][8]  elem = X[b][t*32+lq][ck*8+j]
//   role 2   (V):   T[b][tile32][4 c][128 d][8]    elem = V[b][t*32+c*8+j][d]
// grid (64 tiles, 8 b, 3 roles), block 256.
// ---------------------------------------------------------------------------
__global__ __launch_bounds__(256)
void prep_kernel(const float* __restrict__ Q, const float* __restrict__ K,
                 const float* __restrict__ V, unsigned short* __restrict__ Qt,
                 unsigned short* __restrict__ Kt, unsigned short* __restrict__ Vt) {
  __shared__ __align__(16) float Tf[32][132];
  const int ti = blockIdx.x, b = blockIdx.y, role = blockIdx.z;
  const int tid = threadIdx.x;
  const float* src = role == 0 ? Q : (role == 1 ? K : V);
  {
    const int row = tid >> 3, seg = (tid & 7) * 16;
    const float4* sp = (const float4*)(src + ((size_t)b * SS + ti * 32 + row) * DD + seg);
#pragma unroll
    for (int j = 0; j < 4; ++j) *(float4*)&Tf[row][seg + 4 * j] = sp[j];
  }
  __syncthreads();
  if (role < 2) {
    unsigned short* dst = (role == 0 ? Qt : Kt) + ((size_t)b * 64 + ti) * 4096;
#pragma unroll
    for (int e = 0; e < 2; ++e) {
      const int c = 2 * tid + e, lq = c & 31, ck = c >> 5;
      const float4 a = *(const float4*)&Tf[lq][ck * 8];
      const float4 d = *(const float4*)&Tf[lq][ck * 8 + 4];
      bf16x8 o;
      o[0] = (short)f2bf(a.x); o[1] = (short)f2bf(a.y);
      o[2] = (short)f2bf(a.z); o[3] = (short)f2bf(a.w);
      o[4] = (short)f2bf(d.x); o[5] = (short)f2bf(d.y);
      o[6] = (short)f2bf(d.z); o[7] = (short)f2bf(d.w);
      *(bf16x8*)(dst + c * 8) = o;
    }
  } else {
    unsigned short* dst = Vt + ((size_t)b * 64 + ti) * 4096;
#pragma unroll
    for (int e = 0; e < 2; ++e) {
      const int chunk = 2 * tid + e, cc = chunk >> 7, d = chunk & 127;
      bf16x8 o;
#pragma unroll
      for (int j = 0; j < 8; ++j) o[j] = (short)f2bf(Tf[cc * 8 + j][d]);
      *(bf16x8*)(dst + chunk * 8) = o;
    }
  }
}

// ---------------------------------------------------------------------------
// attn: single fused kernel.
// Phase A: per-wave QK over its 512-key slice, online (max2, sum2) stats
//          (2-tile ILP), 4-wave LDS reduce -> per-row lb = -(m + log2 s).
// Phase B: QK recompute (pipelined 1 tile ahead), W = exp2(fma(s,C1,lb))
//          stored nontemporal via per-wave LDS gather (full-line segments),
//          P redistributed lane<->lane+32 via permlane32_swap, PV from
//          fragment-tiled Vt with V-frags prefetched one tile ahead.
// grid (64 qb of 32 rows, 8 b), block 256 = 4 waves = 4-way k-split.
// ---------------------------------------------------------------------------
__global__ __launch_bounds__(256, 2)
void attn_kernel(const unsigned short* __restrict__ Qt,
                 const unsigned short* __restrict__ Kt,
                 const unsigned short* __restrict__ Vt,
                 float* __restrict__ W, float* __restrict__ Out) {
  __shared__ __align__(16) float PW[4][32][40];  // per-wave P gather, rotated cols
  __shared__ __align__(16) float R[32][132];
  __shared__ float2 sms[4][32];

  const int b = blockIdx.y, qb = blockIdx.x;
  const int q0 = qb * 32;
  const int tid = threadIdx.x;
  const int lane = tid & 63, wv = tid >> 6;
  const int lq = lane & 31, h2 = lane >> 5;
  const f32x16 ZERO16 = {0, 0, 0, 0, 0, 0, 0, 0, 0, 0, 0, 0, 0, 0, 0, 0};

  {
    float* Rf = &R[0][0];
    for (int idx = tid; idx < 32 * 132; idx += 256) Rf[idx] = 0.f;
  }

  const unsigned short* qbase = Qt + ((size_t)b * 64 + (q0 >> 5)) * 4096;
  bf16x8 qh[8];
#pragma unroll
  for (int ds = 0; ds < 8; ++ds)
    qh[ds] = *(const bf16x8*)(qbase + ((ds * 2 + h2) * 32 + lq) * 8);

  const unsigned short* const ktw = Kt + ((size_t)b * 64 + wv * 16) * 4096;
  const unsigned short* const vtw = Vt + ((size_t)b * 64 + wv * 16) * 4096;

  // ================= Phase A: stats over this wave's 512 keys =============
  float m2 = -1e30f, s2 = 0.f;
#pragma unroll
  for (int kp = 0; kp < 8; ++kp) {
    const unsigned short* kb0 = ktw + (2 * kp) * 4096;
    const unsigned short* kb1 = kb0 + 4096;
    bf16x8 a0[8], a1[8];
#pragma unroll
    for (int ds = 0; ds < 8; ++ds) {
      a0[ds] = *(const bf16x8*)(kb0 + ((ds * 2 + h2) * 32 + lq) * 8);
      a1[ds] = *(const bf16x8*)(kb1 + ((ds * 2 + h2) * 32 + lq) * 8);
    }
    f32x16 acc0 = ZERO16, acc1 = ZERO16;
#pragma unroll
    for (int ds = 0; ds < 8; ++ds) {
      acc0 = MFMA32(a0[ds], qh[ds], acc0);
      acc1 = MFMA32(a1[ds], qh[ds], acc1);
    }
    float tm0 = acc0[0], tm1 = acc1[0];
#pragma unroll
    for (int r = 1; r < 16; ++r) {
      tm0 = fmaxf(tm0, acc0[r]);
      tm1 = fmaxf(tm1, acc1[r]);
    }
    const float nm2 = fmaxf(m2, fmaxf(tm0, tm1) * C1);
    float add = 0.f;
#pragma unroll
    for (int r = 0; r < 16; ++r)
      add += EXP2(fmaf(acc0[r], C1, -nm2)) + EXP2(fmaf(acc1[r], C1, -nm2));
    s2 = s2 * EXP2(m2 - nm2) + add;
    m2 = nm2;
  }
  {  // combine the two half-wave partials (lanes l <-> l+32 share q)
    const float mo = __shfl_xor(m2, 32);
    const float so = __shfl_xor(s2, 32);
    const float nm = fmaxf(m2, mo);
    s2 = s2 * EXP2(m2 - nm) + so * EXP2(mo - nm);
    if (h2 == 0) sms[wv][lq] = make_float2(nm, s2);
  }
  __syncthreads();
  // ---- 4-wave stats reduce -> lb (every thread, for its q-row lq) ----
  float lb;
  {
    float2 pj[4];
    float m = -1e30f;
#pragma unroll
    for (int j = 0; j < 4; ++j) {
      pj[j] = sms[j][lq];
      m = fmaxf(m, pj[j].x);
    }
    float s = 0.f;
#pragma unroll
    for (int j = 0; j < 4; ++j) s += pj[j].y * EXP2(pj[j].x - m);
    lb = -(m + __log2f(s));
  }

  // ================= Phase B: normalize + W + PV ==========================
  // ---- W-store gather pointers (per-lane constants) ----
  float* pwwr[4];
#pragma unroll
  for (int g = 0; g < 4; ++g)
    pwwr[g] = &PW[wv][lq][(8 * g + 4 * h2 + lq * 4) & 31];
  const int gq8 = lane >> 3, gks = lane & 7;
  const float* pwrd[4];
  float* wgb[4];
#pragma unroll
  for (int i = 0; i < 4; ++i) {
    const int row = i * 8 + gq8;
    pwrd[i] = &PW[wv][row][(gks * 4 + row * 4) & 31];
    wgb[i] = W + ((size_t)b * SS + q0 + row) * SS + gks * 4;
  }

  f32x16 accO[4];
#pragma unroll
  for (int dt = 0; dt < 4; ++dt) accO[dt] = ZERO16;

  // pipeline prologue: QK + V-frag loads for this wave's tile 0
  f32x16 acc = ZERO16;
  bf16x8 vb[8];
  {
    bf16x8 ah[8];
#pragma unroll
    for (int ds = 0; ds < 8; ++ds)
      ah[ds] = *(const bf16x8*)(ktw + ((ds * 2 + h2) * 32 + lq) * 8);
#pragma unroll
    for (int ds = 0; ds < 8; ++ds) acc = MFMA32(ah[ds], qh[ds], acc);
#pragma unroll
    for (int kk = 0; kk < 2; ++kk)
#pragma unroll
      for (int dt = 0; dt < 4; ++dt)
        vb[kk * 4 + dt] =
            *(const bf16x8*)(vtw + ((kk * 2 + h2) * 128 + dt * 32 + lq) * 8);
  }

  for (int kt = 0; kt < 16; ++kt) {
    const int kb = (wv * 16 + kt) * 32;
    // ---- prefetch next tile's K and V fragments ----
    bf16x8 ahn[8], vbn[8];
    if (kt < 15) {
      const unsigned short* kn = ktw + (kt + 1) * 4096;
      const unsigned short* vn = vtw + (kt + 1) * 4096;
#pragma unroll
      for (int ds = 0; ds < 8; ++ds)
        ahn[ds] = *(const bf16x8*)(kn + ((ds * 2 + h2) * 32 + lq) * 8);
#pragma unroll
      for (int kk = 0; kk < 2; ++kk)
#pragma unroll
        for (int dt = 0; dt < 4; ++dt)
          vbn[kk * 4 + dt] =
              *(const bf16x8*)(vn + ((kk * 2 + h2) * 128 + dt * 32 + lq) * 8);
    }
    // ---- softmax: p = exp2(s*C1 + lb); LDS gather write; bf16 pack ----
    // D layout: col(q)=lq, key row = (r&3) + 8*(r>>2) + 4*h2
    unsigned int U[8];
#pragma unroll
    for (int g = 0; g < 4; ++g) {
      const float p0 = EXP2(fmaf(acc[4 * g + 0], C1, lb));
      const float p1 = EXP2(fmaf(acc[4 * g + 1], C1, lb));
      const float p2 = EXP2(fmaf(acc[4 * g + 2], C1, lb));
      const float p3 = EXP2(fmaf(acc[4 * g + 3], C1, lb));
      *(float4*)pwwr[g] = make_float4(p0, p1, p2, p3);
      U[2 * g] = (unsigned)f2bf(p0) | ((unsigned)f2bf(p1) << 16);
      U[2 * g + 1] = (unsigned)f2bf(p2) | ((unsigned)f2bf(p3) << 16);
    }
    // ---- next tile's QK (independent; hides LDS write latency) ----
    f32x16 accn = ZERO16;
    if (kt < 15) {
#pragma unroll
      for (int ds = 0; ds < 8; ++ds) accn = MFMA32(ahn[ds], qh[ds], accn);
    }
    // ---- gathered nontemporal W stores (full-line segments) ----
#pragma unroll
    for (int i = 0; i < 4; ++i) nt_store4(pwrd[i], wgb[i] + kb);
    // ---- P redistribution via permlane32_swap (lane l <-> l+32) ----
    const uint2v s02 = PSWAP(U[0], U[2]);
    const uint2v s13 = PSWAP(U[1], U[3]);
    const uint2v s46 = PSWAP(U[4], U[6]);
    const uint2v s57 = PSWAP(U[5], U[7]);
    uint4v w0, w1;
    w0.x = s02.x; w0.y = s13.x; w0.z = s02.y; w0.w = s13.y;
    w1.x = s46.x; w1.y = s57.x; w1.z = s46.y; w1.w = s57.y;
    const bf16x8 pa0 = __builtin_bit_cast(bf16x8, w0);
    const bf16x8 pa1 = __builtin_bit_cast(bf16x8, w1);
    // ---- PV (V-frags prefetched last iter) ----
#pragma unroll
    for (int dt = 0; dt < 4; ++dt) accO[dt] = MFMA32(pa0, vb[dt], accO[dt]);
#pragma unroll
    for (int dt = 0; dt < 4; ++dt) accO[dt] = MFMA32(pa1, vb[4 + dt], accO[dt]);
    acc = accn;
#pragma unroll
    for (int j = 0; j < 8; ++j) vb[j] = vbn[j];
  }

  // ---- 4-way O reduction in LDS ----
  __syncthreads();
#pragma unroll
  for (int ph = 0; ph < 4; ++ph) {
    if (wv == ph) {
#pragma unroll
      for (int dt = 0; dt < 4; ++dt) {
#pragma unroll
        for (int r = 0; r < 16; ++r) {
          const int q = (r & 3) + 8 * (r >> 2) + 4 * h2;
          R[q][dt * 32 + lq] += accO[dt][r];
        }
      }
    }
    __syncthreads();
  }
  {
    const int row = tid >> 3, c0 = (tid & 7) * 16;
    float* ob = Out + ((size_t)b * SS + q0 + row) * DD + c0;
#pragma unroll
    for (int j = 0; j < 4; ++j) nt_store4(&R[row][c0 + 4 * j], ob + 4 * j);
  }
}

// ---------------------------------------------------------------------------
extern "C" void kernel_launch(void* const* d_in, const int* in_sizes, int n_in,
                              void* d_out, int out_size, void* d_ws, size_t ws_size,
                              hipStream_t stream) {
  const float* Q = (const float*)d_in[0];
  const float* K = (const float*)d_in[1];
  const float* V = (const float*)d_in[2];
  float* out = (float*)d_out;
  float* W = out + (size_t)NQK;  // attn_weights region of d_out

  char* ws = (char*)d_ws;  // 12 MB used
  unsigned short* Qt = (unsigned short*)(ws);
  unsigned short* Kt = (unsigned short*)(ws + ((size_t)4 << 20));
  unsigned short* Vt = (unsigned short*)(ws + ((size_t)8 << 20));

  prep_kernel<<<dim3(64, 8, 3), 256, 0, stream>>>(Q, K, V, Qt, Kt, Vt);
  attn_kernel<<<dim3(64, 8), 256, 0, stream>>>(Qt, Kt, Vt, W, out);
}

// Round 9
// 63.538 us; speedup vs baseline: 4.6203x; 1.0482x over previous
//
#include <hip/hip_runtime.h>
#include <hip/hip_bf16.h>

#define NB 8
#define SS 2048
#define DD 128
#define NQK (NB * SS * DD)

typedef __attribute__((ext_vector_type(8))) short bf16x8;
typedef __attribute__((ext_vector_type(16))) float f32x16;
typedef __attribute__((ext_vector_type(4))) float f32x4;
typedef __attribute__((ext_vector_type(4))) unsigned int uint4v;
typedef __attribute__((ext_vector_type(2))) unsigned int uint2v;

static constexpr float C1 = 0.08838834764831845f * 1.4426950408889634f;  // SCALE*log2(e)

#define MFMA32(a, b, c) __builtin_amdgcn_mfma_f32_32x32x16_bf16(a, b, c, 0, 0, 0)
#define PSWAP(a, b) __builtin_amdgcn_permlane32_swap(a, b, false, false)

#if __has_builtin(__builtin_amdgcn_exp2f)
#define EXP2 __builtin_amdgcn_exp2f
#else
#define EXP2 exp2f
#endif

__device__ __forceinline__ unsigned short f2bf(float x) {
  __hip_bfloat16 h = __float2bfloat16(x);  // RNE
  unsigned short r;
  __builtin_memcpy(&r, &h, 2);
  return r;
}

__device__ __forceinline__ void nt_store4(const float* src, float* dst) {
  f32x4 v;
  __builtin_memcpy(&v, src, 16);
  __builtin_nontemporal_store(v, (f32x4*)dst);
}

// ---------------------------------------------------------------------------
// prep: fp32 -> bf16 fragment-tiled layouts.
//   role 0/1 (Q/K): T[b][tile32][16 ck][32 lq][8]  elem = X[b][t*32+lq][ck*8+j]
//   role 2   (V):   T[b][tile32][4 c][128 d][8]    elem = V[b][t*32+c*8+j][d]
// grid (64 tiles, 8 b, 3 roles), block 256.
// ---------------------------------------------------------------------------
__global__ __launch_bounds__(256)
void prep_kernel(const float* __restrict__ Q, const float* __restrict__ K,
                 const float* __restrict__ V, unsigned short* __restrict__ Qt,
                 unsigned short* __restrict__ Kt, unsigned short* __restrict__ Vt) {
  __shared__ __align__(16) float Tf[32][132];
  const int ti = blockIdx.x, b = blockIdx.y, role = blockIdx.z;
  const int tid = threadIdx.x;
  const float* src = role == 0 ? Q : (role == 1 ? K : V);
  {
    const int row = tid >> 3, seg = (tid & 7) * 16;
    const float4* sp = (const float4*)(src + ((size_t)b * SS + ti * 32 + row) * DD + seg);
#pragma unroll
    for (int j = 0; j < 4; ++j) *(float4*)&Tf[row][seg + 4 * j] = sp[j];
  }
  __syncthreads();
  if (role < 2) {
    unsigned short* dst = (role == 0 ? Qt : Kt) + ((size_t)b * 64 + ti) * 4096;
#pragma unroll
    for (int e = 0; e < 2; ++e) {
      const int c = 2 * tid + e, lq = c & 31, ck = c >> 5;
      const float4 a = *(const float4*)&Tf[lq][ck * 8];
      const float4 d = *(const float4*)&Tf[lq][ck * 8 + 4];
      bf16x8 o;
      o[0] = (short)f2bf(a.x); o[1] = (short)f2bf(a.y);
      o[2] = (short)f2bf(a.z); o[3] = (short)f2bf(a.w);
      o[4] = (short)f2bf(d.x); o[5] = (short)f2bf(d.y);
      o[6] = (short)f2bf(d.z); o[7] = (short)f2bf(d.w);
      *(bf16x8*)(dst + c * 8) = o;
    }
  } else {
    unsigned short* dst = Vt + ((size_t)b * 64 + ti) * 4096;
#pragma unroll
    for (int e = 0; e < 2; ++e) {
      const int chunk = 2 * tid + e, cc = chunk >> 7, d = chunk & 127;
      bf16x8 o;
#pragma unroll
      for (int j = 0; j < 8; ++j) o[j] = (short)f2bf(Tf[cc * 8 + j][d]);
      *(bf16x8*)(dst + chunk * 8) = o;
    }
  }
}

// ---------------------------------------------------------------------------
// attn: single fused kernel.
// Phase A: per-wave QK over its 512-key slice, online stats, 4-wave reduce.
// Phase B: QK recompute (pipelined), W = exp2(fma(s,C1,lb)) via LDS gather +
// nontemporal full-line stores, permlane P redistribution, PV MFMA.
// XCD-batch swizzle: b = blockIdx&7 so each XCD's L2 holds ONE batch's K/V.
// kt-phase stagger: tile order rotated per (qb,wv) to spread concurrent W
// stores across all 16 column phases (HBM channel decorrelation).
// grid 512 linear, block 256 = 4 waves = 4-way k-split.
// ---------------------------------------------------------------------------
__global__ __launch_bounds__(256, 2)
void attn_kernel(const unsigned short* __restrict__ Qt,
                 const unsigned short* __restrict__ Kt,
                 const unsigned short* __restrict__ Vt,
                 float* __restrict__ W, float* __restrict__ Out) {
  __shared__ __align__(16) float PW[4][32][40];  // per-wave P gather, rotated cols
  __shared__ __align__(16) float R[32][132];
  __shared__ float2 sms[4][32];

  const int bid = blockIdx.x;
  const int b = bid & 7, qb = bid >> 3;  // XCD-batch swizzle
  const int q0 = qb * 32;
  const int tid = threadIdx.x;
  const int lane = tid & 63, wv = tid >> 6;
  const int lq = lane & 31, h2 = lane >> 5;
  const int stag = (4 * qb + wv) & 15;  // store channel-phase stagger
  const f32x16 ZERO16 = {0, 0, 0, 0, 0, 0, 0, 0, 0, 0, 0, 0, 0, 0, 0, 0};

  {
    float* Rf = &R[0][0];
    for (int idx = tid; idx < 32 * 132; idx += 256) Rf[idx] = 0.f;
  }

  const unsigned short* qbase = Qt + ((size_t)b * 64 + (q0 >> 5)) * 4096;
  bf16x8 qh[8];
#pragma unroll
  for (int ds = 0; ds < 8; ++ds)
    qh[ds] = *(const bf16x8*)(qbase + ((ds * 2 + h2) * 32 + lq) * 8);

  const unsigned short* const ktw = Kt + ((size_t)b * 64 + wv * 16) * 4096;
  const unsigned short* const vtw = Vt + ((size_t)b * 64 + wv * 16) * 4096;

  // ================= Phase A: stats over this wave's 512 keys =============
  float m2 = -1e30f, s2 = 0.f;
#pragma unroll
  for (int kp = 0; kp < 8; ++kp) {
    const unsigned short* kb0 = ktw + (2 * kp) * 4096;
    const unsigned short* kb1 = kb0 + 4096;
    bf16x8 a0[8], a1[8];
#pragma unroll
    for (int ds = 0; ds < 8; ++ds) {
      a0[ds] = *(const bf16x8*)(kb0 + ((ds * 2 + h2) * 32 + lq) * 8);
      a1[ds] = *(const bf16x8*)(kb1 + ((ds * 2 + h2) * 32 + lq) * 8);
    }
    f32x16 acc0 = ZERO16, acc1 = ZERO16;
#pragma unroll
    for (int ds = 0; ds < 8; ++ds) {
      acc0 = MFMA32(a0[ds], qh[ds], acc0);
      acc1 = MFMA32(a1[ds], qh[ds], acc1);
    }
    float tm0 = acc0[0], tm1 = acc1[0];
#pragma unroll
    for (int r = 1; r < 16; ++r) {
      tm0 = fmaxf(tm0, acc0[r]);
      tm1 = fmaxf(tm1, acc1[r]);
    }
    const float nm2 = fmaxf(m2, fmaxf(tm0, tm1) * C1);
    float add = 0.f;
#pragma unroll
    for (int r = 0; r < 16; ++r)
      add += EXP2(fmaf(acc0[r], C1, -nm2)) + EXP2(fmaf(acc1[r], C1, -nm2));
    s2 = s2 * EXP2(m2 - nm2) + add;
    m2 = nm2;
  }
  {  // combine the two half-wave partials (lanes l <-> l+32 share q)
    const float mo = __shfl_xor(m2, 32);
    const float so = __shfl_xor(s2, 32);
    const float nm = fmaxf(m2, mo);
    s2 = s2 * EXP2(m2 - nm) + so * EXP2(mo - nm);
    if (h2 == 0) sms[wv][lq] = make_float2(nm, s2);
  }
  __syncthreads();
  // ---- 4-wave stats reduce -> lb (every thread, for its q-row lq) ----
  float lb;
  {
    float2 pj[4];
    float m = -1e30f;
#pragma unroll
    for (int j = 0; j < 4; ++j) {
      pj[j] = sms[j][lq];
      m = fmaxf(m, pj[j].x);
    }
    float s = 0.f;
#pragma unroll
    for (int j = 0; j < 4; ++j) s += pj[j].y * EXP2(pj[j].x - m);
    lb = -(m + __log2f(s));
  }

  // ================= Phase B: normalize + W + PV ==========================
  // ---- W-store gather pointers (per-lane constants) ----
  float* pwwr[4];
#pragma unroll
  for (int g = 0; g < 4; ++g)
    pwwr[g] = &PW[wv][lq][(8 * g + 4 * h2 + lq * 4) & 31];
  const int gq8 = lane >> 3, gks = lane & 7;
  const float* pwrd[4];
  float* wgb[4];
#pragma unroll
  for (int i = 0; i < 4; ++i) {
    const int row = i * 8 + gq8;
    pwrd[i] = &PW[wv][row][(gks * 4 + row * 4) & 31];
    wgb[i] = W + ((size_t)b * SS + q0 + row) * SS + gks * 4;
  }

  f32x16 accO[4];
#pragma unroll
  for (int dt = 0; dt < 4; ++dt) accO[dt] = ZERO16;

  // pipeline prologue: QK + V-frag loads for this wave's first (staggered) tile
  f32x16 acc = ZERO16;
  bf16x8 vb[8];
  {
    const unsigned short* k0 = ktw + stag * 4096;
    const unsigned short* v0 = vtw + stag * 4096;
    bf16x8 ah[8];
#pragma unroll
    for (int ds = 0; ds < 8; ++ds)
      ah[ds] = *(const bf16x8*)(k0 + ((ds * 2 + h2) * 32 + lq) * 8);
#pragma unroll
    for (int ds = 0; ds < 8; ++ds) acc = MFMA32(ah[ds], qh[ds], acc);
#pragma unroll
    for (int kk = 0; kk < 2; ++kk)
#pragma unroll
      for (int dt = 0; dt < 4; ++dt)
        vb[kk * 4 + dt] =
            *(const bf16x8*)(v0 + ((kk * 2 + h2) * 128 + dt * 32 + lq) * 8);
  }

  for (int kt = 0; kt < 16; ++kt) {
    const int lt = (kt + stag) & 15;            // this wave's staggered tile
    const int kb = (wv * 16 + lt) * 32;
    // ---- prefetch next tile's K and V fragments ----
    bf16x8 ahn[8], vbn[8];
    if (kt < 15) {
      const int ln = (kt + 1 + stag) & 15;
      const unsigned short* kn = ktw + ln * 4096;
      const unsigned short* vn = vtw + ln * 4096;
#pragma unroll
      for (int ds = 0; ds < 8; ++ds)
        ahn[ds] = *(const bf16x8*)(kn + ((ds * 2 + h2) * 32 + lq) * 8);
#pragma unroll
      for (int kk = 0; kk < 2; ++kk)
#pragma unroll
        for (int dt = 0; dt < 4; ++dt)
          vbn[kk * 4 + dt] =
              *(const bf16x8*)(vn + ((kk * 2 + h2) * 128 + dt * 32 + lq) * 8);
    }
    // ---- softmax: p = exp2(s*C1 + lb); LDS gather write; bf16 pack ----
    // D layout: col(q)=lq, key row = (r&3) + 8*(r>>2) + 4*h2
    unsigned int U[8];
#pragma unroll
    for (int g = 0; g < 4; ++g) {
      const float p0 = EXP2(fmaf(acc[4 * g + 0], C1, lb));
      const float p1 = EXP2(fmaf(acc[4 * g + 1], C1, lb));
      const float p2 = EXP2(fmaf(acc[4 * g + 2], C1, lb));
      const float p3 = EXP2(fmaf(acc[4 * g + 3], C1, lb));
      *(float4*)pwwr[g] = make_float4(p0, p1, p2, p3);
      U[2 * g] = (unsigned)f2bf(p0) | ((unsigned)f2bf(p1) << 16);
      U[2 * g + 1] = (unsigned)f2bf(p2) | ((unsigned)f2bf(p3) << 16);
    }
    // ---- next tile's QK (independent; hides LDS write latency) ----
    f32x16 accn = ZERO16;
    if (kt < 15) {
#pragma unroll
      for (int ds = 0; ds < 8; ++ds) accn = MFMA32(ahn[ds], qh[ds], accn);
    }
    // ---- gathered nontemporal W stores (full-line segments) ----
#pragma unroll
    for (int i = 0; i < 4; ++i) nt_store4(pwrd[i], wgb[i] + kb);
    // ---- P redistribution via permlane32_swap (lane l <-> l+32) ----
    const uint2v s02 = PSWAP(U[0], U[2]);
    const uint2v s13 = PSWAP(U[1], U[3]);
    const uint2v s46 = PSWAP(U[4], U[6]);
    const uint2v s57 = PSWAP(U[5], U[7]);
    uint4v w0, w1;
    w0.x = s02.x; w0.y = s13.x; w0.z = s02.y; w0.w = s13.y;
    w1.x = s46.x; w1.y = s57.x; w1.z = s46.y; w1.w = s57.y;
    const bf16x8 pa0 = __builtin_bit_cast(bf16x8, w0);
    const bf16x8 pa1 = __builtin_bit_cast(bf16x8, w1);
    // ---- PV (V-frags prefetched last iter) ----
#pragma unroll
    for (int dt = 0; dt < 4; ++dt) accO[dt] = MFMA32(pa0, vb[dt], accO[dt]);
#pragma unroll
    for (int dt = 0; dt < 4; ++dt) accO[dt] = MFMA32(pa1, vb[4 + dt], accO[dt]);
    acc = accn;
#pragma unroll
    for (int j = 0; j < 8; ++j) vb[j] = vbn[j];
  }

  // ---- 4-way O reduction in LDS ----
  __syncthreads();
#pragma unroll
  for (int ph = 0; ph < 4; ++ph) {
    if (wv == ph) {
#pragma unroll
      for (int dt = 0; dt < 4; ++dt) {
#pragma unroll
        for (int r = 0; r < 16; ++r) {
          const int q = (r & 3) + 8 * (r >> 2) + 4 * h2;
          R[q][dt * 32 + lq] += accO[dt][r];
        }
      }
    }
    __syncthreads();
  }
  {
    const int row = tid >> 3, c0 = (tid & 7) * 16;
    float* ob = Out + ((size_t)b * SS + q0 + row) * DD + c0;
#pragma unroll
    for (int j = 0; j < 4; ++j) nt_store4(&R[row][c0 + 4 * j], ob + 4 * j);
  }
}

// ---------------------------------------------------------------------------
extern "C" void kernel_launch(void* const* d_in, const int* in_sizes, int n_in,
                              void* d_out, int out_size, void* d_ws, size_t ws_size,
                              hipStream_t stream) {
  const float* Q = (const float*)d_in[0];
  const float* K = (const float*)d_in[1];
  const float* V = (const float*)d_in[2];
  float* out = (float*)d_out;
  float* W = out + (size_t)NQK;  // attn_weights region of d_out

  char* ws = (char*)d_ws;  // 12 MB used
  unsigned short* Qt = (unsigned short*)(ws);
  unsigned short* Kt = (unsigned short*)(ws + ((size_t)4 << 20));
  unsigned short* Vt = (unsigned short*)(ws + ((size_t)8 << 20));

  prep_kernel<<<dim3(64, 8, 3), 256, 0, stream>>>(Q, K, V, Qt, Kt, Vt);
  attn_kernel<<<512, 256, 0, stream>>>(Qt, Kt, Vt, W, out);
}